// Round 2
// baseline (649.666 us; speedup 1.0000x reference)
//
#include <hip/hip_runtime.h>
#include <cstdint>

// DetNet NMS, round 2: replace the single-block bitonic sort (379us, 91
// barrier-bound stages on one CU) with an O(M^2) exact-rank computation
// spread across the chip, leaving only greedy NMS serial.
//
//   K1 (32 blocks):  key64[i] = (desc_monotone(score)<<16)|i ; zero out; V=0
//   K2 (128 blocks): rank(i) = #{j: key64_j < key64_i} via LDS-tiled scan;
//                    scatter sorted boxes + d rows for valid i; count V.
//                    (valid <=> score>0 <=> dkey<0x7FFFFFFF; all valid sort
//                     before all invalid, so valid ranks are exactly [0,V))
//   K3 (1 block, 4 waves): greedy NMS over ranks [0,V) with a 128-word
//                    suppression bitmask in LDS; per kept box: 2 barriers +
//                    word-sweep that skips saturated words and starts at
//                    word(c) (kept index increases monotonically).
//
// All decision-critical FP math uses __f*_rn (no FMA contraction) with the
// exact op order of the jnp reference — round 1 matched at absmax 0.0.

#define M_TOT 8192
#define NMS_T 0.3f
#define INF_C 0x3FFFFFFF

// ws layout (bytes):           offset    size
//   key64[8192]  (u64)              0   65536
//   boxes_srt[8192] (float4)    65536  131072
//   d_srt[8192*5] (float)      196608  163840
//   vcnt (u32)                 360448       4
#define WS_KEY   0
#define WS_BOX   65536
#define WS_D     196608
#define WS_VCNT  360448

__device__ __forceinline__ uint32_t desc_key(float sv) {
    uint32_t u = __float_as_uint(sv);
    uint32_t m = (u & 0x80000000u) ? ~u : (u | 0x80000000u); // asc monotone
    return ~m;                                               // desc
}

__global__ __launch_bounds__(256) void k1_keys(
    const float* __restrict__ det, const float* __restrict__ offsets,
    const float* __restrict__ scales, const float* __restrict__ bounds,
    unsigned long long* __restrict__ key64, unsigned int* __restrict__ vcnt,
    float* __restrict__ out)
{
    int i = blockIdx.x * 256 + threadIdx.x;   // grid = 32 blocks -> 8192
    if (i == 0) *vcnt = 0u;
    // zero the whole output (harness poisons it with 0xAA)
    for (int u = i; u < M_TOT * 5; u += 32 * 256) out[u] = 0.0f;
    int g = i >> 10;
    float raw_s = det[i * 5 + 0];
    float cx    = det[i * 5 + 1];
    float cy    = det[i * 5 + 2];
    float score = __fadd_rn(offsets[g * 5 + 0], __fmul_rn(raw_s, scales[g * 5 + 0]));
    float L  = bounds[g * 4 + 0], R  = bounds[g * 4 + 1];
    float Tb = bounds[g * 4 + 2], Bb = bounds[g * 4 + 3];
    bool valid = (cx < R) && (cx > L) && (cy < Bb) && (cy > Tb);
    float sv = valid ? score : -1.0f;
    key64[i] = ((unsigned long long)desc_key(sv) << 16) | (unsigned)i;
}

__device__ __forceinline__ int scatter_one(
    int i, int rank, unsigned long long key,
    const float* __restrict__ det, const float* __restrict__ offsets,
    const float* __restrict__ scales,
    float4* __restrict__ boxes_srt, float* __restrict__ d_srt)
{
    uint32_t dkey = (uint32_t)(key >> 16);
    if (dkey >= 0x7FFFFFFFu) return 0;   // invalid (score <= 0): row stays zero
    int g = i >> 10;
    float d0 = __fadd_rn(offsets[g*5+0], __fmul_rn(det[i*5+0], scales[g*5+0]));
    float d1 = __fadd_rn(offsets[g*5+1], __fmul_rn(det[i*5+1], scales[g*5+1]));
    float d2 = __fadd_rn(offsets[g*5+2], __fmul_rn(det[i*5+2], scales[g*5+2]));
    float d3 = __fadd_rn(offsets[g*5+3], __fmul_rn(det[i*5+3], scales[g*5+3]));
    float d4 = __fadd_rn(offsets[g*5+4], __fmul_rn(det[i*5+4], scales[g*5+4]));
    d_srt[rank*5+0] = d0; d_srt[rank*5+1] = d1; d_srt[rank*5+2] = d2;
    d_srt[rank*5+3] = d3; d_srt[rank*5+4] = d4;
    float hw = __fmul_rn(d3, 0.5f), hh = __fmul_rn(d4, 0.5f);
    boxes_srt[rank] = make_float4(__fsub_rn(d1, hw), __fsub_rn(d2, hh),
                                  __fadd_rn(d1, hw), __fadd_rn(d2, hh));
    return 1;
}

__global__ __launch_bounds__(256) void k2_rank(
    const float* __restrict__ det, const float* __restrict__ offsets,
    const float* __restrict__ scales,
    const unsigned long long* __restrict__ key64,
    float4* __restrict__ boxes_srt, float* __restrict__ d_srt,
    unsigned int* __restrict__ vcnt)
{
    __shared__ unsigned long long skey[M_TOT];   // exactly 64 KB
    int t = threadIdx.x;
    for (int u = t; u < M_TOT; u += 256) skey[u] = key64[u];
    __syncthreads();
    // 256 threads = 32 groups of 8; group handles an i-pair, lane-in-group
    // handles j = jq (mod 8) so a wave's 8 concurrent LDS addresses are
    // consecutive u64s (distinct banks; same-addr lanes broadcast).
    int grp = t >> 3;          // 0..31
    int jq  = t & 7;           // j residue class
    int i0 = blockIdx.x * 64 + grp * 2;   // grid = 128 blocks -> 8192
    int i1 = i0 + 1;
    unsigned long long k0 = skey[i0], k1 = skey[i1];
    int c0 = 0, c1 = 0;
    #pragma unroll 4
    for (int it = 0; it < 1024; ++it) {
        unsigned long long kj = skey[it * 8 + jq];
        c0 += (kj < k0);
        c1 += (kj < k1);
    }
    // sum across the 8 lanes of the group (lanes differ in low 3 bits)
    #pragma unroll
    for (int m = 1; m <= 4; m <<= 1) {
        c0 += __shfl_xor(c0, m);
        c1 += __shfl_xor(c1, m);
    }
    if (jq == 0) {
        int nv = scatter_one(i0, c0, k0, det, offsets, scales, boxes_srt, d_srt)
               + scatter_one(i1, c1, k1, det, offsets, scales, boxes_srt, d_srt);
        if (nv) atomicAdd(vcnt, (unsigned)nv);
    }
}

__global__ __launch_bounds__(256) void k3_nms(
    const float4* __restrict__ boxes_srt, const float* __restrict__ d_srt,
    const unsigned int* __restrict__ vcnt, float* __restrict__ out)
{
    __shared__ unsigned long long remv[128];   // bit=1: dead (kept/suppressed/invalid)
    __shared__ unsigned short kept[M_TOT];
    __shared__ int sh_nk;
    __shared__ int sh_min2[2];
    int t = threadIdx.x, lane = t & 63, wv = t >> 6;
    int V = (int)*vcnt;
    int nw = (V + 63) >> 6;
    if (t < 128) {
        unsigned long long w = 0ull;
        int base = t * 64;
        if (base >= V)            w = ~0ull;
        else if (base + 64 > V)   w = (~0ull) << (V - base);
        remv[t] = w;
    }
    if (t == 0) sh_nk = 0;
    __syncthreads();

    while (true) {
        // ---- find min live rank (words live in remv[0..127], waves 0,1 scan)
        int cand = INF_C;
        if (t < 128) {
            unsigned long long w = remv[t];
            if (w != ~0ull) cand = t * 64 + __builtin_ctzll(~w);
        }
        #pragma unroll
        for (int m = 32; m >= 1; m >>= 1) cand = min(cand, __shfl_xor(cand, m));
        if (lane == 0 && wv < 2) sh_min2[wv] = cand;
        __syncthreads();                           // barrier A
        int c = min(sh_min2[0], sh_min2[1]);
        if (c >= V) break;                          // uniform exit
        if (t == 0) kept[sh_nk++] = (unsigned short)c;

        float4 bc = boxes_srt[c];                   // uniform addr, L2-hot
        float ba = __fmul_rn(fmaxf(__fsub_rn(bc.z, bc.x), 0.0f),
                             fmaxf(__fsub_rn(bc.w, bc.y), 0.0f));
        // ---- suppression sweep: words [word(c), nw), 4 waves round-robin.
        // c is the global min live, so all words < word(c) are saturated.
        for (int wi = (c >> 6) + wv; wi < nw; wi += 4) {
            unsigned long long wbits = remv[wi];    // wave-uniform
            if (wbits == ~0ull) continue;           // saturated, skip
            int j = wi * 64 + lane;
            bool supp = false;
            if (!((wbits >> lane) & 1ull)) {        // live lane
                if (j == c) supp = true;            // mark kept box dead
                else {
                    float4 bj = boxes_srt[j];
                    float aj = __fmul_rn(fmaxf(__fsub_rn(bj.z, bj.x), 0.0f),
                                         fmaxf(__fsub_rn(bj.w, bj.y), 0.0f));
                    float iw = fmaxf(__fsub_rn(fminf(bc.z, bj.z), fmaxf(bc.x, bj.x)), 0.0f);
                    float ih = fmaxf(__fsub_rn(fminf(bc.w, bj.w), fmaxf(bc.y, bj.y)), 0.0f);
                    float inter = __fmul_rn(iw, ih);
                    float uni   = __fsub_rn(__fadd_rn(ba, aj), inter);
                    float iou   = __fdiv_rn(inter, fmaxf(uni, 1e-9f));
                    supp = iou > NMS_T;
                }
            }
            unsigned long long bal = __ballot(supp);
            if (lane == 0) remv[wi] = wbits | bal;  // one writer per word
        }
        __syncthreads();                            // barrier B
    }

    // ---- write kept rows: out[r] = d_s[r] (everything else already zero)
    int nk = sh_nk;
    for (int k = t; k < nk * 5; k += 256) {
        int r = (int)kept[k / 5], ch = k % 5;
        out[r * 5 + ch] = d_srt[r * 5 + ch];
    }
}

extern "C" void kernel_launch(void* const* d_in, const int* in_sizes, int n_in,
                              void* d_out, int out_size, void* d_ws, size_t ws_size,
                              hipStream_t stream) {
    const float* det     = (const float*)d_in[0];
    const float* offsets = (const float*)d_in[1];
    const float* scales  = (const float*)d_in[2];
    const float* bounds  = (const float*)d_in[3];
    float* out = (float*)d_out;
    char* ws = (char*)d_ws;
    unsigned long long* key64 = (unsigned long long*)(ws + WS_KEY);
    float4*             boxes = (float4*)(ws + WS_BOX);
    float*              d_srt = (float*)(ws + WS_D);
    unsigned int*       vcnt  = (unsigned int*)(ws + WS_VCNT);

    k1_keys<<<32, 256, 0, stream>>>(det, offsets, scales, bounds, key64, vcnt, out);
    k2_rank<<<128, 256, 0, stream>>>(det, offsets, scales, key64, boxes, d_srt, vcnt);
    k3_nms<<<1, 256, 0, stream>>>(boxes, d_srt, vcnt, out);
}

// Round 3
// 214.214 us; speedup vs baseline: 3.0328x; 3.0328x over previous
//
#include <hip/hip_runtime.h>
#include <cstdint>

// DetNet NMS, round 3.
//   K1 (32 blocks):  keys + zero output + vcnt=0
//   K2 (128 blocks): exact rank + scatter sorted boxes/d rows (unchanged, verified)
//   K_MASK (128x4 blocks): suppression-bit matrix over ranks:
//                    mask[i][w] bit jj = (j>i && IoU(box_i,box_j)>0.3), j=w*64+jj.
//                    All IoU math (incl. __fdiv_rn, exact ref op order) happens here,
//                    in parallel across the chip — NOT in the serial chain.
//   K3 (1 wave):     serial greedy resolve as pure bit algebra:
//                    dead-vector = 128 u64 words held in 2 VGPRs/lane;
//                    per 64-candidate chunk: one prefetched diagonal word/lane,
//                    resolve via shfl broadcasts (no memory in the decision chain);
//                    per kept box: ONE dwordx4 row load/lane, batched 4 rows/group
//                    (OR idempotent -> pad groups with duplicates) so latencies overlap.
//                    Words < current chunk are never re-read => stale bits harmless.
//
// Round-2 k3 kept as fallback if ws_size < 8.9 MB (host branch on a constant).

#define M_TOT 8192
#define NMS_T 0.3f
#define INF_C 0x3FFFFFFF

// ws layout (bytes)
#define WS_KEY   0          // u64[8192]           65536
#define WS_BOX   65536      // float4[8192]       131072
#define WS_D     196608     // float[40960]       163840
#define WS_VCNT  360448     // u32
#define WS_MASK  524288     // u64[8192*128] = 8 MB
#define WS_NEED  (WS_MASK + (size_t)M_TOT * 128 * 8)

__device__ __forceinline__ uint32_t desc_key(float sv) {
    uint32_t u = __float_as_uint(sv);
    uint32_t m = (u & 0x80000000u) ? ~u : (u | 0x80000000u); // asc monotone
    return ~m;                                               // desc
}

__global__ __launch_bounds__(256) void k1_keys(
    const float* __restrict__ det, const float* __restrict__ offsets,
    const float* __restrict__ scales, const float* __restrict__ bounds,
    unsigned long long* __restrict__ key64, unsigned int* __restrict__ vcnt,
    float* __restrict__ out)
{
    int i = blockIdx.x * 256 + threadIdx.x;
    if (i == 0) *vcnt = 0u;
    for (int u = i; u < M_TOT * 5; u += 32 * 256) out[u] = 0.0f;
    int g = i >> 10;
    float raw_s = det[i * 5 + 0];
    float cx    = det[i * 5 + 1];
    float cy    = det[i * 5 + 2];
    float score = __fadd_rn(offsets[g * 5 + 0], __fmul_rn(raw_s, scales[g * 5 + 0]));
    float L  = bounds[g * 4 + 0], R  = bounds[g * 4 + 1];
    float Tb = bounds[g * 4 + 2], Bb = bounds[g * 4 + 3];
    bool valid = (cx < R) && (cx > L) && (cy < Bb) && (cy > Tb);
    float sv = valid ? score : -1.0f;
    key64[i] = ((unsigned long long)desc_key(sv) << 16) | (unsigned)i;
}

__device__ __forceinline__ int scatter_one(
    int i, int rank, unsigned long long key,
    const float* __restrict__ det, const float* __restrict__ offsets,
    const float* __restrict__ scales,
    float4* __restrict__ boxes_srt, float* __restrict__ d_srt)
{
    uint32_t dkey = (uint32_t)(key >> 16);
    if (dkey >= 0x7FFFFFFFu) return 0;   // score <= 0: row stays zero
    int g = i >> 10;
    float d0 = __fadd_rn(offsets[g*5+0], __fmul_rn(det[i*5+0], scales[g*5+0]));
    float d1 = __fadd_rn(offsets[g*5+1], __fmul_rn(det[i*5+1], scales[g*5+1]));
    float d2 = __fadd_rn(offsets[g*5+2], __fmul_rn(det[i*5+2], scales[g*5+2]));
    float d3 = __fadd_rn(offsets[g*5+3], __fmul_rn(det[i*5+3], scales[g*5+3]));
    float d4 = __fadd_rn(offsets[g*5+4], __fmul_rn(det[i*5+4], scales[g*5+4]));
    d_srt[rank*5+0] = d0; d_srt[rank*5+1] = d1; d_srt[rank*5+2] = d2;
    d_srt[rank*5+3] = d3; d_srt[rank*5+4] = d4;
    float hw = __fmul_rn(d3, 0.5f), hh = __fmul_rn(d4, 0.5f);
    boxes_srt[rank] = make_float4(__fsub_rn(d1, hw), __fsub_rn(d2, hh),
                                  __fadd_rn(d1, hw), __fadd_rn(d2, hh));
    return 1;
}

__global__ __launch_bounds__(256) void k2_rank(
    const float* __restrict__ det, const float* __restrict__ offsets,
    const float* __restrict__ scales,
    const unsigned long long* __restrict__ key64,
    float4* __restrict__ boxes_srt, float* __restrict__ d_srt,
    unsigned int* __restrict__ vcnt)
{
    __shared__ unsigned long long skey[M_TOT];
    int t = threadIdx.x;
    for (int u = t; u < M_TOT; u += 256) skey[u] = key64[u];
    __syncthreads();
    int grp = t >> 3;
    int jq  = t & 7;
    int i0 = blockIdx.x * 64 + grp * 2;
    int i1 = i0 + 1;
    unsigned long long k0 = skey[i0], k1 = skey[i1];
    int c0 = 0, c1 = 0;
    #pragma unroll 4
    for (int it = 0; it < 1024; ++it) {
        unsigned long long kj = skey[it * 8 + jq];
        c0 += (kj < k0);
        c1 += (kj < k1);
    }
    #pragma unroll
    for (int m = 1; m <= 4; m <<= 1) {
        c0 += __shfl_xor(c0, m);
        c1 += __shfl_xor(c1, m);
    }
    if (jq == 0) {
        int nv = scatter_one(i0, c0, k0, det, offsets, scales, boxes_srt, d_srt)
               + scatter_one(i1, c1, k1, det, offsets, scales, boxes_srt, d_srt);
        if (nv) atomicAdd(vcnt, (unsigned)nv);
    }
}

// mask build: block (bx,by): rows [bx*64, +64), words [by*32, +32)
__global__ __launch_bounds__(256) void k_mask(
    const float4* __restrict__ boxes_srt,
    const unsigned int* __restrict__ vcnt,
    unsigned long long* __restrict__ mask)
{
    __shared__ float4 sb[2048];
    __shared__ float  sa[2048];
    int bx = blockIdx.x, by = blockIdx.y;
    int V = (int)*vcnt;
    if (bx * 64 >= V) return;           // rows never consulted
    if (by * 32 + 31 < bx) return;      // all words strictly below diagonal:
                                        // stale bits land in remv words already consumed
    int tid = threadIdx.x;
    int cbase = by * 2048;
    for (int u = tid; u < 2048; u += 256) {
        float4 b = boxes_srt[cbase + u];
        sb[u] = b;
        sa[u] = __fmul_rn(fmaxf(__fsub_rn(b.z, b.x), 0.0f),
                          fmaxf(__fsub_rn(b.w, b.y), 0.0f));
    }
    __syncthreads();
    int r = bx * 64 + (tid >> 2);
    if (r >= V) return;
    float4 bi = boxes_srt[r];
    float ai = __fmul_rn(fmaxf(__fsub_rn(bi.z, bi.x), 0.0f),
                         fmaxf(__fsub_rn(bi.w, bi.y), 0.0f));
    int w0 = by * 32 + (tid & 3);
    #pragma unroll
    for (int k = 0; k < 8; ++k) {
        int w = w0 + k * 4;
        int jb = (w - by * 32) * 64;     // local column base in LDS
        unsigned long long bits = 0;
        #pragma unroll 4
        for (int jj = 0; jj < 64; ++jj) {
            float4 bj = sb[jb + jj];
            float aj = sa[jb + jj];
            float iw = fmaxf(__fsub_rn(fminf(bi.z, bj.z), fmaxf(bi.x, bj.x)), 0.0f);
            float ih = fmaxf(__fsub_rn(fminf(bi.w, bj.w), fmaxf(bi.y, bj.y)), 0.0f);
            float inter = __fmul_rn(iw, ih);
            float uni   = __fsub_rn(__fadd_rn(ai, aj), inter);
            float iou   = __fdiv_rn(inter, fmaxf(uni, 1e-9f));   // exact ref formula
            int j = w * 64 + jj;
            if (j > r && iou > NMS_T) bits |= 1ull << jj;
        }
        mask[(size_t)r * 128 + w] = bits;
    }
}

// serial greedy resolve: one wave, bit algebra only
__global__ __launch_bounds__(64) void k3_serial(
    const unsigned long long* __restrict__ mask,
    const float* __restrict__ d_srt,
    const unsigned int* __restrict__ vcnt,
    float* __restrict__ out)
{
    __shared__ unsigned short kept[M_TOT];
    int lane = threadIdx.x;
    int V = (int)*vcnt;
    int nc = (V + 63) >> 6;
    // dead-vector: lane holds words 2*lane (r0) and 2*lane+1 (r1)
    unsigned long long r0 = 0ull, r1 = 0ull;
    int nk = 0;
    unsigned long long intra_cur = (nc > 0) ? mask[(size_t)lane * 128 + 0] : 0ull;
    for (int t = 0; t < nc; ++t) {
        int base = t * 64;
        unsigned long long intra_next = 0ull;
        if (t + 1 < nc)   // prefetch next chunk's diagonal word
            intra_next = mask[(size_t)(base + 64 + lane) * 128 + (t + 1)];
        unsigned long long wv0 = __shfl(r0, t >> 1);
        unsigned long long wv1 = __shfl(r1, t >> 1);
        unsigned long long dead = (t & 1) ? wv1 : wv0;
        unsigned long long live = ~dead;
        int rem = V - base;
        if (rem < 64) live &= (1ull << rem) - 1ull;
        unsigned long long kept_mask = 0ull;
        while (live) {                      // uniform: all lanes identical scalars
            int b = __builtin_ctzll(live);
            if (lane == 0) kept[nk] = (unsigned short)(base + b);
            nk++;
            unsigned long long rm = __shfl(intra_cur, b);  // kept box's diag word
            live &= ~rm;
            live &= ~(1ull << b);
            kept_mask |= 1ull << b;
        }
        // OR kept rows into dead-vector, 4 rows per group (dup pad: OR idempotent)
        unsigned long long km = kept_mask;
        while (km) {
            int b0 = __builtin_ctzll(km); km &= km - 1;
            int b1 = b0, b2 = b0, b3 = b0;
            if (km) { b1 = __builtin_ctzll(km); km &= km - 1; }
            if (km) { b2 = __builtin_ctzll(km); km &= km - 1; }
            if (km) { b3 = __builtin_ctzll(km); km &= km - 1; }
            const ulonglong2* p0 = (const ulonglong2*)(mask + (size_t)(base + b0) * 128) + lane;
            const ulonglong2* p1 = (const ulonglong2*)(mask + (size_t)(base + b1) * 128) + lane;
            const ulonglong2* p2 = (const ulonglong2*)(mask + (size_t)(base + b2) * 128) + lane;
            const ulonglong2* p3 = (const ulonglong2*)(mask + (size_t)(base + b3) * 128) + lane;
            ulonglong2 v0 = *p0, v1 = *p1, v2 = *p2, v3 = *p3;
            r0 |= v0.x | v1.x | v2.x | v3.x;
            r1 |= v0.y | v1.y | v2.y | v3.y;
        }
        intra_cur = intra_next;
    }
    __syncthreads();
    for (int k = lane; k < nk; k += 64) {
        int rr = (int)kept[k];
        out[rr * 5 + 0] = d_srt[rr * 5 + 0];
        out[rr * 5 + 1] = d_srt[rr * 5 + 1];
        out[rr * 5 + 2] = d_srt[rr * 5 + 2];
        out[rr * 5 + 3] = d_srt[rr * 5 + 3];
        out[rr * 5 + 4] = d_srt[rr * 5 + 4];
    }
}

// ---- round-2 fallback NMS (used only if ws is too small for the mask) ----
__global__ __launch_bounds__(256) void k3_nms(
    const float4* __restrict__ boxes_srt, const float* __restrict__ d_srt,
    const unsigned int* __restrict__ vcnt, float* __restrict__ out)
{
    __shared__ unsigned long long remv[128];
    __shared__ unsigned short kept[M_TOT];
    __shared__ int sh_nk;
    __shared__ int sh_min2[2];
    int t = threadIdx.x, lane = t & 63, wv = t >> 6;
    int V = (int)*vcnt;
    int nw = (V + 63) >> 6;
    if (t < 128) {
        unsigned long long w = 0ull;
        int base = t * 64;
        if (base >= V)            w = ~0ull;
        else if (base + 64 > V)   w = (~0ull) << (V - base);
        remv[t] = w;
    }
    if (t == 0) sh_nk = 0;
    __syncthreads();
    while (true) {
        int cand = INF_C;
        if (t < 128) {
            unsigned long long w = remv[t];
            if (w != ~0ull) cand = t * 64 + __builtin_ctzll(~w);
        }
        #pragma unroll
        for (int m = 32; m >= 1; m >>= 1) cand = min(cand, __shfl_xor(cand, m));
        if (lane == 0 && wv < 2) sh_min2[wv] = cand;
        __syncthreads();
        int c = min(sh_min2[0], sh_min2[1]);
        if (c >= V) break;
        if (t == 0) kept[sh_nk++] = (unsigned short)c;
        float4 bc = boxes_srt[c];
        float ba = __fmul_rn(fmaxf(__fsub_rn(bc.z, bc.x), 0.0f),
                             fmaxf(__fsub_rn(bc.w, bc.y), 0.0f));
        for (int wi = (c >> 6) + wv; wi < nw; wi += 4) {
            unsigned long long wbits = remv[wi];
            if (wbits == ~0ull) continue;
            int j = wi * 64 + lane;
            bool supp = false;
            if (!((wbits >> lane) & 1ull)) {
                if (j == c) supp = true;
                else {
                    float4 bj = boxes_srt[j];
                    float aj = __fmul_rn(fmaxf(__fsub_rn(bj.z, bj.x), 0.0f),
                                         fmaxf(__fsub_rn(bj.w, bj.y), 0.0f));
                    float iw = fmaxf(__fsub_rn(fminf(bc.z, bj.z), fmaxf(bc.x, bj.x)), 0.0f);
                    float ih = fmaxf(__fsub_rn(fminf(bc.w, bj.w), fmaxf(bc.y, bj.y)), 0.0f);
                    float inter = __fmul_rn(iw, ih);
                    float uni   = __fsub_rn(__fadd_rn(ba, aj), inter);
                    float iou   = __fdiv_rn(inter, fmaxf(uni, 1e-9f));
                    supp = iou > NMS_T;
                }
            }
            unsigned long long bal = __ballot(supp);
            if (lane == 0) remv[wi] = wbits | bal;
        }
        __syncthreads();
    }
    int nk = sh_nk;
    for (int k = t; k < nk * 5; k += 256) {
        int r = (int)kept[k / 5], ch = k % 5;
        out[r * 5 + ch] = d_srt[r * 5 + ch];
    }
}

extern "C" void kernel_launch(void* const* d_in, const int* in_sizes, int n_in,
                              void* d_out, int out_size, void* d_ws, size_t ws_size,
                              hipStream_t stream) {
    const float* det     = (const float*)d_in[0];
    const float* offsets = (const float*)d_in[1];
    const float* scales  = (const float*)d_in[2];
    const float* bounds  = (const float*)d_in[3];
    float* out = (float*)d_out;
    char* ws = (char*)d_ws;
    unsigned long long* key64 = (unsigned long long*)(ws + WS_KEY);
    float4*             boxes = (float4*)(ws + WS_BOX);
    float*              d_srt = (float*)(ws + WS_D);
    unsigned int*       vcnt  = (unsigned int*)(ws + WS_VCNT);
    unsigned long long* mask  = (unsigned long long*)(ws + WS_MASK);

    k1_keys<<<32, 256, 0, stream>>>(det, offsets, scales, bounds, key64, vcnt, out);
    k2_rank<<<128, 256, 0, stream>>>(det, offsets, scales, key64, boxes, d_srt, vcnt);
    if (ws_size >= WS_NEED) {   // constant per problem: graph-safe branch
        k_mask<<<dim3(128, 4), 256, 0, stream>>>(boxes, vcnt, mask);
        k3_serial<<<1, 64, 0, stream>>>(mask, d_srt, vcnt, out);
    } else {
        k3_nms<<<1, 256, 0, stream>>>(boxes, d_srt, vcnt, out);
    }
}

// Round 4
// 208.305 us; speedup vs baseline: 3.1188x; 1.0284x over previous
//
#include <hip/hip_runtime.h>
#include <cstdint>

// DetNet NMS, round 4.
//   K2 (128 blocks): build all 8192 keys in-LDS per block (identical FP in every
//        block), count V (plain store, identical-value races benign), zero out
//        slice, exact rank via LDS scan, scatter sorted boxes + d rows.
//   K_MASK (128x4): suppression-bit matrix, upper-triangle-of-live-region only:
//        per thread skip words w < r>>6 (never consulted) and w*64 >= V.
//        LDS chunk stride padded 64->65: group lanes (tid&3) land on distinct
//        banks (round-3 had 6.3M bank conflicts from the 1024B stride).
//   K3 (1 wave): serial greedy resolve, K-independent critical path:
//        dead_t = reduce64(gather(word t of kept rows thru chunk t-2,
//                 issued at chunk t-1)) | carry(shfl of prefetched next-word
//                 of chunk t-1's rows). Diagonal word prefetched likewise.
//        No memory op is issued and awaited in the same chunk.
//
// All decision-critical FP math uses __f*_rn in exact ref op order (absmax 0.0
// in rounds 1-3).

#define M_TOT 8192
#define NMS_T 0.3f

// ws layout (bytes)
#define WS_BOX   65536      // float4[8192]       131072
#define WS_D     196608     // float[40960]       163840
#define WS_VCNT  360448     // u32
#define WS_MASK  524288     // u64[8192*128] = 8 MB

__device__ __forceinline__ uint32_t desc_key(float sv) {
    uint32_t u = __float_as_uint(sv);
    uint32_t m = (u & 0x80000000u) ? ~u : (u | 0x80000000u); // asc monotone
    return ~m;                                               // desc
}

__device__ __forceinline__ int scatter_one(
    int i, int rank, unsigned long long key,
    const float* __restrict__ det, const float* __restrict__ offsets,
    const float* __restrict__ scales,
    float4* __restrict__ boxes_srt, float* __restrict__ d_srt)
{
    uint32_t dkey = (uint32_t)(key >> 16);
    if (dkey >= 0x7FFFFFFFu) return 0;   // score <= 0: row stays zero
    int g = i >> 10;
    float d0 = __fadd_rn(offsets[g*5+0], __fmul_rn(det[i*5+0], scales[g*5+0]));
    float d1 = __fadd_rn(offsets[g*5+1], __fmul_rn(det[i*5+1], scales[g*5+1]));
    float d2 = __fadd_rn(offsets[g*5+2], __fmul_rn(det[i*5+2], scales[g*5+2]));
    float d3 = __fadd_rn(offsets[g*5+3], __fmul_rn(det[i*5+3], scales[g*5+3]));
    float d4 = __fadd_rn(offsets[g*5+4], __fmul_rn(det[i*5+4], scales[g*5+4]));
    d_srt[rank*5+0] = d0; d_srt[rank*5+1] = d1; d_srt[rank*5+2] = d2;
    d_srt[rank*5+3] = d3; d_srt[rank*5+4] = d4;
    float hw = __fmul_rn(d3, 0.5f), hh = __fmul_rn(d4, 0.5f);
    boxes_srt[rank] = make_float4(__fsub_rn(d1, hw), __fsub_rn(d2, hh),
                                  __fadd_rn(d1, hw), __fadd_rn(d2, hh));
    return 1;
}

__global__ __launch_bounds__(256) void k2_rank(
    const float* __restrict__ det, const float* __restrict__ offsets,
    const float* __restrict__ scales, const float* __restrict__ bounds,
    float4* __restrict__ boxes_srt, float* __restrict__ d_srt,
    unsigned int* __restrict__ vcnt, float* __restrict__ out)
{
    __shared__ unsigned long long skey[M_TOT];   // 64 KB
    __shared__ float soff[40], sscl[40], sbnd[32];
    __shared__ int sV;
    int t = threadIdx.x;
    if (t == 0) sV = 0;
    if (t < 40) { soff[t] = offsets[t]; sscl[t] = scales[t]; }
    if (t < 32) { sbnd[t] = bounds[t]; }
    __syncthreads();

    // build all 8192 keys locally (identical in every block) + count V
    int cnt = 0;
    for (int u = t; u < M_TOT; u += 256) {
        int g = u >> 10;
        float raw_s = det[u * 5 + 0];
        float cx    = det[u * 5 + 1];
        float cy    = det[u * 5 + 2];
        float score = __fadd_rn(soff[g * 5 + 0], __fmul_rn(raw_s, sscl[g * 5 + 0]));
        float L  = sbnd[g * 4 + 0], R  = sbnd[g * 4 + 1];
        float Tb = sbnd[g * 4 + 2], Bb = sbnd[g * 4 + 3];
        bool valid = (cx < R) && (cx > L) && (cy < Bb) && (cy > Tb);
        float sv = valid ? score : -1.0f;
        uint32_t dk = desc_key(sv);
        skey[u] = ((unsigned long long)dk << 16) | (unsigned)u;
        cnt += (dk < 0x7FFFFFFFu);          // sv > 0
    }
    atomicAdd(&sV, cnt);
    // zero this block's slice of out (harness poisons it to 0xAA)
    {
        int zb = blockIdx.x * 320;
        for (int z = zb + t; z < zb + 320; z += 256) out[z] = 0.0f;
    }
    __syncthreads();
    if (t == 0) *vcnt = (unsigned)sV;        // 128 identical stores: benign

    // exact rank: 32 groups of 8; group -> i-pair, lane-in-group -> j mod 8
    int grp = t >> 3;
    int jq  = t & 7;
    int i0 = blockIdx.x * 64 + grp * 2;
    int i1 = i0 + 1;
    unsigned long long k0 = skey[i0], k1 = skey[i1];
    int c0 = 0, c1 = 0;
    #pragma unroll 4
    for (int it = 0; it < 1024; ++it) {
        unsigned long long kj = skey[it * 8 + jq];
        c0 += (kj < k0);
        c1 += (kj < k1);
    }
    #pragma unroll
    for (int m = 1; m <= 4; m <<= 1) {
        c0 += __shfl_xor(c0, m);
        c1 += __shfl_xor(c1, m);
    }
    if (jq == 0) {
        scatter_one(i0, c0, k0, det, offsets, scales, boxes_srt, d_srt);
        scatter_one(i1, c1, k1, det, offsets, scales, boxes_srt, d_srt);
    }
}

// mask build: block (bx,by): rows [bx*64,+64), words [by*32,+32)
__global__ __launch_bounds__(256) void k_mask(
    const float4* __restrict__ boxes_srt,
    const unsigned int* __restrict__ vcnt,
    unsigned long long* __restrict__ mask)
{
    __shared__ float4 sb[32 * 65];   // chunk stride 65: kills 4-way bank conflict
    __shared__ float  sa[32 * 65];
    int V = (int)*vcnt;
    int bx = blockIdx.x, by = blockIdx.y;
    if (bx * 64 >= V) return;        // rows never consulted
    if (by * 2048 >= V) return;      // columns never consulted
    if (by * 32 + 31 < bx) return;   // entirely below diagonal: never consulted
    int nc = (V + 63) >> 6;
    int tid = threadIdx.x;
    int cbase = by * 2048;
    for (int u = tid; u < 2048; u += 256) {
        float4 b = boxes_srt[cbase + u];
        int c = u >> 6, jj = u & 63;
        sb[c * 65 + jj] = b;
        sa[c * 65 + jj] = __fmul_rn(fmaxf(__fsub_rn(b.z, b.x), 0.0f),
                                    fmaxf(__fsub_rn(b.w, b.y), 0.0f));
    }
    __syncthreads();
    int r = bx * 64 + (tid >> 2);
    if (r >= V) return;
    float4 bi = boxes_srt[r];
    float ai = __fmul_rn(fmaxf(__fsub_rn(bi.z, bi.x), 0.0f),
                         fmaxf(__fsub_rn(bi.w, bi.y), 0.0f));
    int rw = r >> 6;                 // words < rw of row r are never read
    #pragma unroll
    for (int k = 0; k < 8; ++k) {
        int w = by * 32 + (tid & 3) + k * 4;
        if (w < rw || w >= nc) continue;
        int c = (tid & 3) + k * 4;
        unsigned long long bits = 0;
        #pragma unroll 4
        for (int jj = 0; jj < 64; ++jj) {
            float4 bj = sb[c * 65 + jj];
            float aj = sa[c * 65 + jj];
            float iw = fmaxf(__fsub_rn(fminf(bi.z, bj.z), fmaxf(bi.x, bj.x)), 0.0f);
            float ih = fmaxf(__fsub_rn(fminf(bi.w, bj.w), fmaxf(bi.y, bj.y)), 0.0f);
            float inter = __fmul_rn(iw, ih);
            float uni   = __fsub_rn(__fadd_rn(ai, aj), inter);
            float iou   = __fdiv_rn(inter, fmaxf(uni, 1e-9f));
            int j = w * 64 + jj;
            if (j > r && iou > NMS_T) bits |= 1ull << jj;
        }
        mask[(size_t)r * 128 + w] = bits;
    }
}

// serial greedy resolve: one wave, all loads issued one chunk ahead of use
__global__ __launch_bounds__(64) void k3_serial(
    const unsigned long long* __restrict__ mask,
    const float* __restrict__ d_srt,
    const unsigned int* __restrict__ vcnt,
    float* __restrict__ out)
{
    __shared__ unsigned short kept[M_TOT];
    int lane = threadIdx.x;
    int V = (int)*vcnt;
    int nc = (V + 63) >> 6;
    int nk = 0;                                  // uniform
    unsigned long long diag = 0, nxt = 0, gath = 0, carry = 0;
    if (nc > 0) {
        diag = mask[(size_t)lane * 128 + 0];     // word 0 of rows 0..63
        if (nc > 1) nxt = mask[(size_t)lane * 128 + 1];
    }
    for (int t = 0; t < nc; ++t) {
        int base = t * 64;
        // ---- issue all chunk-(t+1) loads now ----
        unsigned long long diag_n = 0, nxt_n = 0, gath_n = 0;
        if (t + 1 < nc) {
            diag_n = mask[(size_t)(base + 64 + lane) * 128 + (t + 1)];
            if (t + 2 < nc)
                nxt_n = mask[(size_t)(base + 64 + lane) * 128 + (t + 2)];
            for (int g = lane; g < nk; g += 64)          // kept thru chunk t-1
                gath_n |= mask[(size_t)kept[g] * 128 + (t + 1)];
        }
        // ---- dead word for this chunk (loads issued at chunk t-1) ----
        unsigned long long dead = gath;
        #pragma unroll
        for (int m = 1; m <= 32; m <<= 1) dead |= __shfl_xor(dead, m);
        dead |= carry;                            // chunk t-1 rows' contribution
        unsigned long long live = ~dead;
        int rem = V - base;
        if (rem < 64) live &= (1ull << rem) - 1ull;
        unsigned long long keptmask = 0;
        while (live) {                            // uniform scalar loop
            int b = __builtin_ctzll(live);
            if (lane == 0) kept[nk] = (unsigned short)(base + b);
            nk++;
            unsigned long long rm = __shfl(diag, b);   // kept box's diag word
            live &= ~rm;
            live &= ~(1ull << b);
            keptmask |= 1ull << b;
        }
        // carry: this chunk's kept rows -> word t+1 (nxt prefetched at chunk t)
        carry = 0;
        unsigned long long km = keptmask;
        while (km) {
            int b = __builtin_ctzll(km); km &= km - 1;
            carry |= __shfl(nxt, b);
        }
        diag = diag_n; nxt = nxt_n; gath = gath_n;
    }
    __syncthreads();
    for (int k = lane; k < nk; k += 64) {
        int rr = (int)kept[k];
        out[rr * 5 + 0] = d_srt[rr * 5 + 0];
        out[rr * 5 + 1] = d_srt[rr * 5 + 1];
        out[rr * 5 + 2] = d_srt[rr * 5 + 2];
        out[rr * 5 + 3] = d_srt[rr * 5 + 3];
        out[rr * 5 + 4] = d_srt[rr * 5 + 4];
    }
}

extern "C" void kernel_launch(void* const* d_in, const int* in_sizes, int n_in,
                              void* d_out, int out_size, void* d_ws, size_t ws_size,
                              hipStream_t stream) {
    const float* det     = (const float*)d_in[0];
    const float* offsets = (const float*)d_in[1];
    const float* scales  = (const float*)d_in[2];
    const float* bounds  = (const float*)d_in[3];
    float* out = (float*)d_out;
    char* ws = (char*)d_ws;
    float4*             boxes = (float4*)(ws + WS_BOX);
    float*              d_srt = (float*)(ws + WS_D);
    unsigned int*       vcnt  = (unsigned int*)(ws + WS_VCNT);
    unsigned long long* mask  = (unsigned long long*)(ws + WS_MASK);

    k2_rank<<<128, 256, 0, stream>>>(det, offsets, scales, bounds, boxes, d_srt, vcnt, out);
    k_mask<<<dim3(128, 4), 256, 0, stream>>>(boxes, vcnt, mask);
    k3_serial<<<1, 64, 0, stream>>>(mask, d_srt, vcnt, out);
}

// Round 6
// 179.398 us; speedup vs baseline: 3.6214x; 1.1611x over previous
//
#include <hip/hip_runtime.h>
#include <cstdint>

// DetNet NMS, round 6 (round-5 design, compile-fixed: token-pasting macros
// replaced by an inlined device function; state passed by reference stays in
// registers).
//   K2 (128 blocks): keys in-LDS (identical per block), V count, zero out,
//        exact rank, scatter sorted boxes + d rows. (verified)
//   K_MASK (256x8): suppression-bit matrix, 32 rows x 1024 cols per block,
//        padded LDS (stride 65) conflict-free; triangle + V pruning.
//   K3 (1 wave): serial greedy resolve, zero memory ops on the steady-state
//        critical path:
//        - dead-vector distributed: lane L holds words 2L,2L+1 (r0,r1)
//        - kept rows: one ulonglong2/lane load issued at keep time, applied
//          TWO chunks later (parity slots pa/pb; loads in flight across the
//          loop back edge)
//        - keeps at t-1 -> word t via shfl-carry of prefetched nxt word
//        - diag/nxt words prefetched one chunk ahead
//        - >4 keeps in one chunk (rare): immediate grouped row ORs
//        Unwritten mask words (w < row's own chunk) only pollute dead words
//        already consumed (words are read in increasing chunk order).
//
// All decision-critical FP math uses __f*_rn in exact ref op order (absmax
// 0.0 in rounds 1-4).

#define M_TOT 8192
#define NMS_T 0.3f

// ws layout (bytes)
#define WS_BOX   65536      // float4[8192]
#define WS_D     196608     // float[40960]
#define WS_VCNT  360448     // u32
#define WS_MASK  524288     // u64[8192*128] = 8 MB

__device__ __forceinline__ uint32_t desc_key(float sv) {
    uint32_t u = __float_as_uint(sv);
    uint32_t m = (u & 0x80000000u) ? ~u : (u | 0x80000000u); // asc monotone
    return ~m;                                               // desc
}

__device__ __forceinline__ int scatter_one(
    int i, int rank, unsigned long long key,
    const float* __restrict__ det, const float* __restrict__ offsets,
    const float* __restrict__ scales,
    float4* __restrict__ boxes_srt, float* __restrict__ d_srt)
{
    uint32_t dkey = (uint32_t)(key >> 16);
    if (dkey >= 0x7FFFFFFFu) return 0;   // score <= 0: row stays zero
    int g = i >> 10;
    float d0 = __fadd_rn(offsets[g*5+0], __fmul_rn(det[i*5+0], scales[g*5+0]));
    float d1 = __fadd_rn(offsets[g*5+1], __fmul_rn(det[i*5+1], scales[g*5+1]));
    float d2 = __fadd_rn(offsets[g*5+2], __fmul_rn(det[i*5+2], scales[g*5+2]));
    float d3 = __fadd_rn(offsets[g*5+3], __fmul_rn(det[i*5+3], scales[g*5+3]));
    float d4 = __fadd_rn(offsets[g*5+4], __fmul_rn(det[i*5+4], scales[g*5+4]));
    d_srt[rank*5+0] = d0; d_srt[rank*5+1] = d1; d_srt[rank*5+2] = d2;
    d_srt[rank*5+3] = d3; d_srt[rank*5+4] = d4;
    float hw = __fmul_rn(d3, 0.5f), hh = __fmul_rn(d4, 0.5f);
    boxes_srt[rank] = make_float4(__fsub_rn(d1, hw), __fsub_rn(d2, hh),
                                  __fadd_rn(d1, hw), __fadd_rn(d2, hh));
    return 1;
}

__global__ __launch_bounds__(256) void k2_rank(
    const float* __restrict__ det, const float* __restrict__ offsets,
    const float* __restrict__ scales, const float* __restrict__ bounds,
    float4* __restrict__ boxes_srt, float* __restrict__ d_srt,
    unsigned int* __restrict__ vcnt, float* __restrict__ out)
{
    __shared__ unsigned long long skey[M_TOT];   // 64 KB
    __shared__ float soff[40], sscl[40], sbnd[32];
    __shared__ int sV;
    int t = threadIdx.x;
    if (t == 0) sV = 0;
    if (t < 40) { soff[t] = offsets[t]; sscl[t] = scales[t]; }
    if (t < 32) { sbnd[t] = bounds[t]; }
    __syncthreads();

    int cnt = 0;
    for (int u = t; u < M_TOT; u += 256) {
        int g = u >> 10;
        float raw_s = det[u * 5 + 0];
        float cx    = det[u * 5 + 1];
        float cy    = det[u * 5 + 2];
        float score = __fadd_rn(soff[g * 5 + 0], __fmul_rn(raw_s, sscl[g * 5 + 0]));
        float L  = sbnd[g * 4 + 0], R  = sbnd[g * 4 + 1];
        float Tb = sbnd[g * 4 + 2], Bb = sbnd[g * 4 + 3];
        bool valid = (cx < R) && (cx > L) && (cy < Bb) && (cy > Tb);
        float sv = valid ? score : -1.0f;
        uint32_t dk = desc_key(sv);
        skey[u] = ((unsigned long long)dk << 16) | (unsigned)u;
        cnt += (dk < 0x7FFFFFFFu);          // sv > 0
    }
    atomicAdd(&sV, cnt);
    {
        int zb = blockIdx.x * 320;
        for (int z = zb + t; z < zb + 320; z += 256) out[z] = 0.0f;
    }
    __syncthreads();
    if (t == 0) *vcnt = (unsigned)sV;        // 128 identical stores: benign

    int grp = t >> 3;
    int jq  = t & 7;
    int i0 = blockIdx.x * 64 + grp * 2;
    int i1 = i0 + 1;
    unsigned long long k0 = skey[i0], k1 = skey[i1];
    int c0 = 0, c1 = 0;
    #pragma unroll 4
    for (int it = 0; it < 1024; ++it) {
        unsigned long long kj = skey[it * 8 + jq];
        c0 += (kj < k0);
        c1 += (kj < k1);
    }
    #pragma unroll
    for (int m = 1; m <= 4; m <<= 1) {
        c0 += __shfl_xor(c0, m);
        c1 += __shfl_xor(c1, m);
    }
    if (jq == 0) {
        scatter_one(i0, c0, k0, det, offsets, scales, boxes_srt, d_srt);
        scatter_one(i1, c1, k1, det, offsets, scales, boxes_srt, d_srt);
    }
}

// mask build: block (bx,by): rows [bx*32,+32), words [by*16,+16)
__global__ __launch_bounds__(256) void k_mask(
    const float4* __restrict__ boxes_srt,
    const unsigned int* __restrict__ vcnt,
    unsigned long long* __restrict__ mask)
{
    __shared__ float4 sb[16 * 65];   // padded stride: conflict-free
    __shared__ float  sa[16 * 65];
    int V = (int)*vcnt;
    int bx = blockIdx.x, by = blockIdx.y;
    if (bx * 32 >= V) return;                      // rows never consulted
    if (by * 1024 >= V) return;                    // cols never consulted
    if (by * 16 + 15 < (bx * 32) >> 6) return;     // fully below diagonal
    int nc = (V + 63) >> 6;
    int tid = threadIdx.x;
    int cbase = by * 1024;
    for (int u = tid; u < 1024; u += 256) {
        float4 b = boxes_srt[cbase + u];
        int c = u >> 6, jj = u & 63;
        sb[c * 65 + jj] = b;
        sa[c * 65 + jj] = __fmul_rn(fmaxf(__fsub_rn(b.z, b.x), 0.0f),
                                    fmaxf(__fsub_rn(b.w, b.y), 0.0f));
    }
    __syncthreads();
    int r = bx * 32 + (tid >> 3);
    if (r >= V) return;
    float4 bi = boxes_srt[r];
    float ai = __fmul_rn(fmaxf(__fsub_rn(bi.z, bi.x), 0.0f),
                         fmaxf(__fsub_rn(bi.w, bi.y), 0.0f));
    int rw = r >> 6;                 // words < rw of row r are never read
    #pragma unroll
    for (int k = 0; k < 2; ++k) {
        int wl = (tid & 7) + k * 8;              // local word 0..15
        int w = by * 16 + wl;
        if (w < rw || w >= nc) continue;
        unsigned long long bits = 0;
        #pragma unroll 4
        for (int jj = 0; jj < 64; ++jj) {
            float4 bj = sb[wl * 65 + jj];
            float aj = sa[wl * 65 + jj];
            float iw = fmaxf(__fsub_rn(fminf(bi.z, bj.z), fmaxf(bi.x, bj.x)), 0.0f);
            float ih = fmaxf(__fsub_rn(fminf(bi.w, bj.w), fmaxf(bi.y, bj.y)), 0.0f);
            float inter = __fmul_rn(iw, ih);
            float uni   = __fsub_rn(__fadd_rn(ai, aj), inter);
            float iou   = __fdiv_rn(inter, fmaxf(uni, 1e-9f));
            int j = w * 64 + jj;
            if (j > r && iou > NMS_T) bits |= 1ull << jj;
        }
        mask[(size_t)r * 128 + w] = bits;
    }
}

// ---- one pipeline step of the serial resolve (always inlined; all state in
// registers). T = chunk index; p0..p3/pv = this parity's pending row loads
// (issued at chunk T-2, applied here); diag/nxt = word T / T+1 of chunk T's
// rows; diagn/nxtn = prefetch outputs for chunk T+1.
__device__ __forceinline__ void chunk_step(
    const unsigned long long* __restrict__ mask,
    unsigned short* kept, int lane, int V, int nc, int T,
    int& nk, unsigned long long& r0, unsigned long long& r1,
    unsigned long long& carry,
    ulonglong2& p0, ulonglong2& p1, ulonglong2& p2, ulonglong2& p3, bool& pv,
    unsigned long long diag, unsigned long long nxt,
    unsigned long long& diagn, unsigned long long& nxtn)
{
    int base = T * 64;
    // prefetch chunk T+1's diag/nxt words now
    diagn = 0; nxtn = 0;
    if (T + 1 < nc) {
        diagn = mask[(size_t)(base + 64 + lane) * 128 + (T + 1)];
        if (T + 2 < nc)
            nxtn = mask[(size_t)(base + 64 + lane) * 128 + (T + 2)];
    }
    // apply keeps from chunk T-2 (loads have been in flight for 2 chunks)
    if (pv) {
        r0 |= p0.x | p1.x | p2.x | p3.x;
        r1 |= p0.y | p1.y | p2.y | p3.y;
    }
    pv = false;
    // dead word for this chunk: distributed vector + last chunk's carry
    unsigned long long wv = (T & 1) ? __shfl(r1, T >> 1) : __shfl(r0, T >> 1);
    unsigned long long dead = wv | carry;
    unsigned long long live = ~dead;
    int rem = V - base;
    if (rem < 64) live &= (1ull << rem) - 1ull;
    unsigned long long keptmask = 0;
    while (live) {                       // wave-uniform scalar loop
        int b = __builtin_ctzll(live);
        if (lane == 0) kept[nk] = (unsigned short)(base + b);
        nk++;
        unsigned long long rm = __shfl(diag, b);   // kept box's word T
        live &= ~rm;
        live &= ~(1ull << b);
        keptmask |= 1ull << b;
    }
    // carry: this chunk's keeps -> word T+1 via prefetched nxt
    carry = 0;
    {
        unsigned long long km = keptmask;
        while (km) {
            int b = __builtin_ctzll(km); km &= km - 1;
            carry |= __shfl(nxt, b);
        }
    }
    // issue full-row loads for this chunk's keeps (applied at chunk T+2)
    if (keptmask) {
        unsigned long long km = keptmask;
        int b0 = __builtin_ctzll(km); km &= km - 1;
        int b1 = b0, b2 = b0, b3 = b0;     // dup-pad: OR idempotent
        if (km) { b1 = __builtin_ctzll(km); km &= km - 1; }
        if (km) { b2 = __builtin_ctzll(km); km &= km - 1; }
        if (km) { b3 = __builtin_ctzll(km); km &= km - 1; }
        p0 = *((const ulonglong2*)(mask + (size_t)(base + b0) * 128) + lane);
        p1 = *((const ulonglong2*)(mask + (size_t)(base + b1) * 128) + lane);
        p2 = *((const ulonglong2*)(mask + (size_t)(base + b2) * 128) + lane);
        p3 = *((const ulonglong2*)(mask + (size_t)(base + b3) * 128) + lane);
        pv = true;
        while (km) {    // >4 keeps in one chunk: rare, immediate grouped ORs
            int c0 = __builtin_ctzll(km); km &= km - 1;
            int c1 = c0, c2 = c0, c3 = c0;
            if (km) { c1 = __builtin_ctzll(km); km &= km - 1; }
            if (km) { c2 = __builtin_ctzll(km); km &= km - 1; }
            if (km) { c3 = __builtin_ctzll(km); km &= km - 1; }
            ulonglong2 s0 = *((const ulonglong2*)(mask + (size_t)(base + c0) * 128) + lane);
            ulonglong2 s1 = *((const ulonglong2*)(mask + (size_t)(base + c1) * 128) + lane);
            ulonglong2 s2 = *((const ulonglong2*)(mask + (size_t)(base + c2) * 128) + lane);
            ulonglong2 s3 = *((const ulonglong2*)(mask + (size_t)(base + c3) * 128) + lane);
            r0 |= s0.x | s1.x | s2.x | s3.x;
            r1 |= s0.y | s1.y | s2.y | s3.y;
        }
    }
}

__global__ __launch_bounds__(64) void k3_serial(
    const unsigned long long* __restrict__ mask,
    const float* __restrict__ d_srt,
    const unsigned int* __restrict__ vcnt,
    float* __restrict__ out)
{
    __shared__ unsigned short kept[M_TOT];
    int lane = threadIdx.x;
    int V = (int)*vcnt;
    int nc = (V + 63) >> 6;
    int nk = 0;                                  // wave-uniform
    unsigned long long r0 = 0, r1 = 0;           // lane L: dead words 2L,2L+1
    unsigned long long carry = 0;
    unsigned long long diagA = 0, nxtA = 0, diagB = 0, nxtB = 0;
    ulonglong2 pa0{0,0}, pa1{0,0}, pa2{0,0}, pa3{0,0};
    ulonglong2 pb0{0,0}, pb1{0,0}, pb2{0,0}, pb3{0,0};
    bool pav = false, pbv = false;
    if (nc > 0) {
        diagA = mask[(size_t)lane * 128 + 0];
        if (nc > 1) nxtA = mask[(size_t)lane * 128 + 1];
    }
    for (int t = 0; t < nc; t += 2) {
        chunk_step(mask, kept, lane, V, nc, t,
                   nk, r0, r1, carry, pa0, pa1, pa2, pa3, pav,
                   diagA, nxtA, diagB, nxtB);
        if (t + 1 < nc)
            chunk_step(mask, kept, lane, V, nc, t + 1,
                       nk, r0, r1, carry, pb0, pb1, pb2, pb3, pbv,
                       diagB, nxtB, diagA, nxtA);
    }
    __syncthreads();
    for (int k = lane; k < nk; k += 64) {
        int rr = (int)kept[k];
        out[rr * 5 + 0] = d_srt[rr * 5 + 0];
        out[rr * 5 + 1] = d_srt[rr * 5 + 1];
        out[rr * 5 + 2] = d_srt[rr * 5 + 2];
        out[rr * 5 + 3] = d_srt[rr * 5 + 3];
        out[rr * 5 + 4] = d_srt[rr * 5 + 4];
    }
}

extern "C" void kernel_launch(void* const* d_in, const int* in_sizes, int n_in,
                              void* d_out, int out_size, void* d_ws, size_t ws_size,
                              hipStream_t stream) {
    const float* det     = (const float*)d_in[0];
    const float* offsets = (const float*)d_in[1];
    const float* scales  = (const float*)d_in[2];
    const float* bounds  = (const float*)d_in[3];
    float* out = (float*)d_out;
    char* ws = (char*)d_ws;
    float4*             boxes = (float4*)(ws + WS_BOX);
    float*              d_srt = (float*)(ws + WS_D);
    unsigned int*       vcnt  = (unsigned int*)(ws + WS_VCNT);
    unsigned long long* mask  = (unsigned long long*)(ws + WS_MASK);

    k2_rank<<<128, 256, 0, stream>>>(det, offsets, scales, bounds, boxes, d_srt, vcnt, out);
    k_mask<<<dim3(256, 8), 256, 0, stream>>>(boxes, vcnt, mask);
    k3_serial<<<1, 64, 0, stream>>>(mask, d_srt, vcnt, out);
}

// Round 7
// 178.057 us; speedup vs baseline: 3.6486x; 1.0075x over previous
//
#include <hip/hip_runtime.h>
#include <cstdint>

// DetNet NMS, round 7.
//   K2 (128 blocks): keys in-LDS (identical per block), V count, zero out,
//        exact rank, scatter sorted boxes + d rows; also zeroes the dummy row.
//   K_MASK (256x8): suppression-bit matrix, triangle/V-pruned, padded LDS.
//   K3 (1 wave): serial greedy resolve as a DEPTH-3 modulo-scheduled pipeline:
//        - slots A/B/C rotate; chunk T's diag/nxt1/nxt2 words are loaded at
//          T-3 (slack ~1050 cyc >= ~900 cyc L3 latency, m126)
//        - 8 row loads per chunk, ALWAYS issued (dummy zero row pads unused
//          slots; OR idempotent/zero) -> straight-line load pattern, compiler
//          can emit fine-grained vmcnt instead of conservative drains
//        - rows applied at T+3; keeps reach T+1/T+2 via carry registers
//          (shfl of prefetched words T+1,T+2 of the keeping chunk's rows)
//        - >8 keeps in a chunk (P~1%): immediate in-branch loads+ORs
//        - per-chunk keptmask -> LDS once; output phase expands bitmasks
//        Unwritten mask words only pollute dead words already consumed
//        (words are read in increasing chunk order) — unchanged invariant.
//
// All decision-critical FP math uses __f*_rn in exact ref op order (absmax
// 0.0 in rounds 1-4, 6).

#define M_TOT 8192
#define NMS_T 0.3f

// ws layout (bytes)
#define WS_BOX   65536      // float4[8192]
#define WS_D     196608     // float[40960]
#define WS_VCNT  360448     // u32
#define WS_ZROW  393216     // u64[128] dummy zero row (zeroed by k2)
#define WS_MASK  524288     // u64[8192*128] = 8 MB

__device__ __forceinline__ uint32_t desc_key(float sv) {
    uint32_t u = __float_as_uint(sv);
    uint32_t m = (u & 0x80000000u) ? ~u : (u | 0x80000000u); // asc monotone
    return ~m;                                               // desc
}

__device__ __forceinline__ int scatter_one(
    int i, int rank, unsigned long long key,
    const float* __restrict__ det, const float* __restrict__ offsets,
    const float* __restrict__ scales,
    float4* __restrict__ boxes_srt, float* __restrict__ d_srt)
{
    uint32_t dkey = (uint32_t)(key >> 16);
    if (dkey >= 0x7FFFFFFFu) return 0;   // score <= 0: row stays zero
    int g = i >> 10;
    float d0 = __fadd_rn(offsets[g*5+0], __fmul_rn(det[i*5+0], scales[g*5+0]));
    float d1 = __fadd_rn(offsets[g*5+1], __fmul_rn(det[i*5+1], scales[g*5+1]));
    float d2 = __fadd_rn(offsets[g*5+2], __fmul_rn(det[i*5+2], scales[g*5+2]));
    float d3 = __fadd_rn(offsets[g*5+3], __fmul_rn(det[i*5+3], scales[g*5+3]));
    float d4 = __fadd_rn(offsets[g*5+4], __fmul_rn(det[i*5+4], scales[g*5+4]));
    d_srt[rank*5+0] = d0; d_srt[rank*5+1] = d1; d_srt[rank*5+2] = d2;
    d_srt[rank*5+3] = d3; d_srt[rank*5+4] = d4;
    float hw = __fmul_rn(d3, 0.5f), hh = __fmul_rn(d4, 0.5f);
    boxes_srt[rank] = make_float4(__fsub_rn(d1, hw), __fsub_rn(d2, hh),
                                  __fadd_rn(d1, hw), __fadd_rn(d2, hh));
    return 1;
}

__global__ __launch_bounds__(256) void k2_rank(
    const float* __restrict__ det, const float* __restrict__ offsets,
    const float* __restrict__ scales, const float* __restrict__ bounds,
    float4* __restrict__ boxes_srt, float* __restrict__ d_srt,
    unsigned int* __restrict__ vcnt, unsigned long long* __restrict__ zrow,
    float* __restrict__ out)
{
    __shared__ unsigned long long skey[M_TOT];   // 64 KB
    __shared__ float soff[40], sscl[40], sbnd[32];
    __shared__ int sV;
    int t = threadIdx.x;
    if (t == 0) sV = 0;
    if (t < 40) { soff[t] = offsets[t]; sscl[t] = scales[t]; }
    if (t < 32) { sbnd[t] = bounds[t]; }
    if (blockIdx.x == 0 && t < 128) zrow[t] = 0ull;   // dummy row for k3
    __syncthreads();

    int cnt = 0;
    for (int u = t; u < M_TOT; u += 256) {
        int g = u >> 10;
        float raw_s = det[u * 5 + 0];
        float cx    = det[u * 5 + 1];
        float cy    = det[u * 5 + 2];
        float score = __fadd_rn(soff[g * 5 + 0], __fmul_rn(raw_s, sscl[g * 5 + 0]));
        float L  = sbnd[g * 4 + 0], R  = sbnd[g * 4 + 1];
        float Tb = sbnd[g * 4 + 2], Bb = sbnd[g * 4 + 3];
        bool valid = (cx < R) && (cx > L) && (cy < Bb) && (cy > Tb);
        float sv = valid ? score : -1.0f;
        uint32_t dk = desc_key(sv);
        skey[u] = ((unsigned long long)dk << 16) | (unsigned)u;
        cnt += (dk < 0x7FFFFFFFu);          // sv > 0
    }
    atomicAdd(&sV, cnt);
    {
        int zb = blockIdx.x * 320;
        for (int z = zb + t; z < zb + 320; z += 256) out[z] = 0.0f;
    }
    __syncthreads();
    if (t == 0) *vcnt = (unsigned)sV;        // 128 identical stores: benign

    int grp = t >> 3;
    int jq  = t & 7;
    int i0 = blockIdx.x * 64 + grp * 2;
    int i1 = i0 + 1;
    unsigned long long k0 = skey[i0], k1 = skey[i1];
    int c0 = 0, c1 = 0;
    #pragma unroll 4
    for (int it = 0; it < 1024; ++it) {
        unsigned long long kj = skey[it * 8 + jq];
        c0 += (kj < k0);
        c1 += (kj < k1);
    }
    #pragma unroll
    for (int m = 1; m <= 4; m <<= 1) {
        c0 += __shfl_xor(c0, m);
        c1 += __shfl_xor(c1, m);
    }
    if (jq == 0) {
        scatter_one(i0, c0, k0, det, offsets, scales, boxes_srt, d_srt);
        scatter_one(i1, c1, k1, det, offsets, scales, boxes_srt, d_srt);
    }
}

// mask build: block (bx,by): rows [bx*32,+32), words [by*16,+16)
__global__ __launch_bounds__(256) void k_mask(
    const float4* __restrict__ boxes_srt,
    const unsigned int* __restrict__ vcnt,
    unsigned long long* __restrict__ mask)
{
    __shared__ float4 sb[16 * 65];   // padded stride: conflict-free
    __shared__ float  sa[16 * 65];
    int V = (int)*vcnt;
    int bx = blockIdx.x, by = blockIdx.y;
    if (bx * 32 >= V) return;                      // rows never consulted
    if (by * 1024 >= V) return;                    // cols never consulted
    if (by * 16 + 15 < (bx * 32) >> 6) return;     // fully below diagonal
    int nc = (V + 63) >> 6;
    int tid = threadIdx.x;
    int cbase = by * 1024;
    for (int u = tid; u < 1024; u += 256) {
        float4 b = boxes_srt[cbase + u];
        int c = u >> 6, jj = u & 63;
        sb[c * 65 + jj] = b;
        sa[c * 65 + jj] = __fmul_rn(fmaxf(__fsub_rn(b.z, b.x), 0.0f),
                                    fmaxf(__fsub_rn(b.w, b.y), 0.0f));
    }
    __syncthreads();
    int r = bx * 32 + (tid >> 3);
    if (r >= V) return;
    float4 bi = boxes_srt[r];
    float ai = __fmul_rn(fmaxf(__fsub_rn(bi.z, bi.x), 0.0f),
                         fmaxf(__fsub_rn(bi.w, bi.y), 0.0f));
    int rw = r >> 6;                 // words < rw of row r are never read
    #pragma unroll
    for (int k = 0; k < 2; ++k) {
        int wl = (tid & 7) + k * 8;              // local word 0..15
        int w = by * 16 + wl;
        if (w < rw || w >= nc) continue;
        unsigned long long bits = 0;
        #pragma unroll 4
        for (int jj = 0; jj < 64; ++jj) {
            float4 bj = sb[wl * 65 + jj];
            float aj = sa[wl * 65 + jj];
            float iw = fmaxf(__fsub_rn(fminf(bi.z, bj.z), fmaxf(bi.x, bj.x)), 0.0f);
            float ih = fmaxf(__fsub_rn(fminf(bi.w, bj.w), fmaxf(bi.y, bj.y)), 0.0f);
            float inter = __fmul_rn(iw, ih);
            float uni   = __fsub_rn(__fadd_rn(ai, aj), inter);
            float iou   = __fdiv_rn(inter, fmaxf(uni, 1e-9f));
            int j = w * 64 + jj;
            if (j > r && iou > NMS_T) bits |= 1ull << jj;
        }
        mask[(size_t)r * 128 + w] = bits;
    }
}

// ---- one depth-3 pipeline stage. T = chunk; p[8] = this slot's pending row
// loads (issued at T-3, applied here); d/n1/n2 = words T/T+1/T+2 of chunk
// T's rows (loaded at T-3); on exit they are overwritten with chunk T+3's
// prefetch. cN/cN2 = carries into T / T+1 from chunks T-1/T-2's keeps.
__device__ __forceinline__ void chunk_step(
    const unsigned long long* __restrict__ mask,
    const unsigned long long* __restrict__ zrow,
    unsigned long long* ck, int lane, int V, int nc, int T,
    unsigned long long& r0, unsigned long long& r1,
    unsigned long long& cN, unsigned long long& cN2,
    ulonglong2 (&p)[8],
    unsigned long long& d, unsigned long long& n1, unsigned long long& n2)
{
    int base = T * 64;
    // 1. apply pending rows (issued at T-3; >=3 chunks in flight)
    r0 |= p[0].x | p[1].x | p[2].x | p[3].x | p[4].x | p[5].x | p[6].x | p[7].x;
    r1 |= p[0].y | p[1].y | p[2].y | p[3].y | p[4].y | p[5].y | p[6].y | p[7].y;
    // 2. dead word for this chunk
    unsigned long long wv = (T & 1) ? __shfl(r1, T >> 1) : __shfl(r0, T >> 1);
    unsigned long long live = ~(wv | cN);
    int rem = V - base;
    if (rem < 64) live &= (1ull << rem) - 1ull;
    // 3. intra-chunk greedy resolve (registers + shfl only)
    unsigned long long keptmask = 0;
    while (live) {                       // wave-uniform scalar loop
        int b = __builtin_ctzll(live);
        unsigned long long rm = __shfl(d, b);
        keptmask |= 1ull << b;
        live &= ~rm & ~(1ull << b);
    }
    if (lane == 0) ck[T] = keptmask;
    // 4. carries to T+1 / T+2
    unsigned long long c1 = 0, c2 = 0, km = keptmask;
    while (km) {
        int b = __builtin_ctzll(km); km &= km - 1;
        c1 |= __shfl(n1, b);
        c2 |= __shfl(n2, b);
    }
    cN = cN2 | c1;
    cN2 = c2;
    // 5. prefetch chunk T+3's d/n1/n2 (unconditional; clamped, unused if OOB)
    {
        int pr = min(base + 192 + lane, M_TOT - 1);
        const unsigned long long* rp = mask + (size_t)pr * 128;
        d  = rp[min(T + 3, 127)];
        n1 = rp[min(T + 4, 127)];
        n2 = rp[min(T + 5, 127)];
    }
    // 6. 8 unconditional row loads, dummy-padded (applied at T+3)
    km = keptmask;
    #pragma unroll
    for (int q = 0; q < 8; ++q) {
        bool has = (km != 0ull);
        int b = has ? __builtin_ctzll(km) : 0;
        const ulonglong2* ptr = has
            ? ((const ulonglong2*)(mask + (size_t)(base + b) * 128) + lane)
            : ((const ulonglong2*)zrow + lane);
        p[q] = *ptr;
        km &= km - 1;                    // km==0 stays 0
    }
    // 7. overflow: >8 keeps in one chunk (P ~1%): immediate in-branch ORs
    if (km) {
        while (km) {
            int b = __builtin_ctzll(km); km &= km - 1;
            ulonglong2 s = *((const ulonglong2*)(mask + (size_t)(base + b) * 128) + lane);
            r0 |= s.x; r1 |= s.y;
        }
    }
}

__global__ __launch_bounds__(64) void k3_serial(
    const unsigned long long* __restrict__ mask,
    const unsigned long long* __restrict__ zrow,
    const float* __restrict__ d_srt,
    const unsigned int* __restrict__ vcnt,
    float* __restrict__ out)
{
    __shared__ unsigned long long ck[128];       // per-chunk keptmask
    int lane = threadIdx.x;
    int V = (int)*vcnt;
    int nc = (V + 63) >> 6;
    ck[lane] = 0ull; ck[64 + lane] = 0ull;
    unsigned long long r0 = 0, r1 = 0;           // lane L: dead words 2L,2L+1
    unsigned long long cN = 0, cN2 = 0;
    ulonglong2 pA[8], pB[8], pC[8];
    #pragma unroll
    for (int q = 0; q < 8; ++q) { pA[q] = ulonglong2{0,0}; pB[q] = ulonglong2{0,0}; pC[q] = ulonglong2{0,0}; }
    // prologue: slots for chunks 0,1,2 (clamped rows; junk unused if chunk >= nc)
    unsigned long long dA, n1A, n2A, dB, n1B, n2B, dC, n1C, n2C;
    {
        const unsigned long long* rp0 = mask + (size_t)lane * 128;
        dA = rp0[0]; n1A = rp0[1]; n2A = rp0[2];
        const unsigned long long* rp1 = mask + (size_t)(64 + lane) * 128;
        dB = rp1[1]; n1B = rp1[2]; n2B = rp1[3];
        const unsigned long long* rp2 = mask + (size_t)(128 + lane) * 128;
        dC = rp2[2]; n1C = rp2[3]; n2C = rp2[4];
    }
    for (int t = 0; t < nc; t += 3) {
        chunk_step(mask, zrow, ck, lane, V, nc, t,     r0, r1, cN, cN2, pA, dA, n1A, n2A);
        if (t + 1 < nc)
            chunk_step(mask, zrow, ck, lane, V, nc, t + 1, r0, r1, cN, cN2, pB, dB, n1B, n2B);
        if (t + 2 < nc)
            chunk_step(mask, zrow, ck, lane, V, nc, t + 2, r0, r1, cN, cN2, pC, dC, n1C, n2C);
    }
    __syncthreads();
    // output: expand per-chunk keptmasks (order irrelevant for stores)
    #pragma unroll
    for (int h = 0; h < 2; ++h) {
        unsigned long long m = ck[h * 64 + lane];
        while (m) {
            int b = __builtin_ctzll(m); m &= m - 1;
            int rr = (h * 64 + lane) * 64 + b;
            out[rr * 5 + 0] = d_srt[rr * 5 + 0];
            out[rr * 5 + 1] = d_srt[rr * 5 + 1];
            out[rr * 5 + 2] = d_srt[rr * 5 + 2];
            out[rr * 5 + 3] = d_srt[rr * 5 + 3];
            out[rr * 5 + 4] = d_srt[rr * 5 + 4];
        }
    }
}

extern "C" void kernel_launch(void* const* d_in, const int* in_sizes, int n_in,
                              void* d_out, int out_size, void* d_ws, size_t ws_size,
                              hipStream_t stream) {
    const float* det     = (const float*)d_in[0];
    const float* offsets = (const float*)d_in[1];
    const float* scales  = (const float*)d_in[2];
    const float* bounds  = (const float*)d_in[3];
    float* out = (float*)d_out;
    char* ws = (char*)d_ws;
    float4*             boxes = (float4*)(ws + WS_BOX);
    float*              d_srt = (float*)(ws + WS_D);
    unsigned int*       vcnt  = (unsigned int*)(ws + WS_VCNT);
    unsigned long long* zrow  = (unsigned long long*)(ws + WS_ZROW);
    unsigned long long* mask  = (unsigned long long*)(ws + WS_MASK);

    k2_rank<<<128, 256, 0, stream>>>(det, offsets, scales, bounds, boxes, d_srt, vcnt, zrow, out);
    k_mask<<<dim3(256, 8), 256, 0, stream>>>(boxes, vcnt, mask);
    k3_serial<<<1, 64, 0, stream>>>(mask, zrow, d_srt, vcnt, out);
}

// Round 8
// 167.977 us; speedup vs baseline: 3.8676x; 1.0600x over previous
//
#include <hip/hip_runtime.h>
#include <cstdint>

// DetNet NMS, round 8.
// Round-7 post-mortem: k3's per-chunk cost (~2100 cyc) was INSENSITIVE to
// memory-pipeline depth because the serial chain was ~25 chained __shfl
// (= ds_bpermute, ~120 cyc LDS latency each), not vmcnt. All broadcast
// indices are wave-uniform -> use v_readlane (__builtin_amdgcn_readlane,
// ~VALU latency) instead. Memory pipeline from round 7 kept unchanged
// (depth-3 rotation, 8 dummy-padded unconditional row loads per chunk).
//
//   K2 (128 blocks): keys in-LDS (identical per block), V count, zero out,
//        exact rank, scatter sorted boxes + d rows; zeroes the dummy row.
//   K_MASK (256x8): suppression-bit matrix, triangle/V-pruned, padded LDS.
//   K3 (1 wave): serial greedy resolve, depth-3 modulo-scheduled pipeline,
//        broadcasts via readlane. Unwritten mask words only pollute dead
//        words already consumed (read order is increasing chunk index).
//
// All decision-critical FP math uses __f*_rn in exact ref op order (absmax
// 0.0 in rounds 1-4, 6, 7).

#define M_TOT 8192
#define NMS_T 0.3f

// ws layout (bytes)
#define WS_BOX   65536      // float4[8192]
#define WS_D     196608     // float[40960]
#define WS_VCNT  360448     // u32
#define WS_ZROW  393216     // u64[128] dummy zero row (zeroed by k2)
#define WS_MASK  524288     // u64[8192*128] = 8 MB

__device__ __forceinline__ uint32_t desc_key(float sv) {
    uint32_t u = __float_as_uint(sv);
    uint32_t m = (u & 0x80000000u) ? ~u : (u | 0x80000000u); // asc monotone
    return ~m;                                               // desc
}

// wave-uniform-index 64-bit broadcast via v_readlane (~VALU latency;
// __shfl would emit ds_bpermute at ~120 cyc LDS latency)
__device__ __forceinline__ unsigned long long rdlane64(unsigned long long v, int lane) {
    unsigned lo = (unsigned)__builtin_amdgcn_readlane((int)(unsigned)v, lane);
    unsigned hi = (unsigned)__builtin_amdgcn_readlane((int)(unsigned)(v >> 32), lane);
    return ((unsigned long long)hi << 32) | lo;
}

__device__ __forceinline__ int scatter_one(
    int i, int rank, unsigned long long key,
    const float* __restrict__ det, const float* __restrict__ offsets,
    const float* __restrict__ scales,
    float4* __restrict__ boxes_srt, float* __restrict__ d_srt)
{
    uint32_t dkey = (uint32_t)(key >> 16);
    if (dkey >= 0x7FFFFFFFu) return 0;   // score <= 0: row stays zero
    int g = i >> 10;
    float d0 = __fadd_rn(offsets[g*5+0], __fmul_rn(det[i*5+0], scales[g*5+0]));
    float d1 = __fadd_rn(offsets[g*5+1], __fmul_rn(det[i*5+1], scales[g*5+1]));
    float d2 = __fadd_rn(offsets[g*5+2], __fmul_rn(det[i*5+2], scales[g*5+2]));
    float d3 = __fadd_rn(offsets[g*5+3], __fmul_rn(det[i*5+3], scales[g*5+3]));
    float d4 = __fadd_rn(offsets[g*5+4], __fmul_rn(det[i*5+4], scales[g*5+4]));
    d_srt[rank*5+0] = d0; d_srt[rank*5+1] = d1; d_srt[rank*5+2] = d2;
    d_srt[rank*5+3] = d3; d_srt[rank*5+4] = d4;
    float hw = __fmul_rn(d3, 0.5f), hh = __fmul_rn(d4, 0.5f);
    boxes_srt[rank] = make_float4(__fsub_rn(d1, hw), __fsub_rn(d2, hh),
                                  __fadd_rn(d1, hw), __fadd_rn(d2, hh));
    return 1;
}

__global__ __launch_bounds__(256) void k2_rank(
    const float* __restrict__ det, const float* __restrict__ offsets,
    const float* __restrict__ scales, const float* __restrict__ bounds,
    float4* __restrict__ boxes_srt, float* __restrict__ d_srt,
    unsigned int* __restrict__ vcnt, unsigned long long* __restrict__ zrow,
    float* __restrict__ out)
{
    __shared__ unsigned long long skey[M_TOT];   // 64 KB
    __shared__ float soff[40], sscl[40], sbnd[32];
    __shared__ int sV;
    int t = threadIdx.x;
    if (t == 0) sV = 0;
    if (t < 40) { soff[t] = offsets[t]; sscl[t] = scales[t]; }
    if (t < 32) { sbnd[t] = bounds[t]; }
    if (blockIdx.x == 0 && t < 128) zrow[t] = 0ull;   // dummy row for k3
    __syncthreads();

    int cnt = 0;
    for (int u = t; u < M_TOT; u += 256) {
        int g = u >> 10;
        float raw_s = det[u * 5 + 0];
        float cx    = det[u * 5 + 1];
        float cy    = det[u * 5 + 2];
        float score = __fadd_rn(soff[g * 5 + 0], __fmul_rn(raw_s, sscl[g * 5 + 0]));
        float L  = sbnd[g * 4 + 0], R  = sbnd[g * 4 + 1];
        float Tb = sbnd[g * 4 + 2], Bb = sbnd[g * 4 + 3];
        bool valid = (cx < R) && (cx > L) && (cy < Bb) && (cy > Tb);
        float sv = valid ? score : -1.0f;
        uint32_t dk = desc_key(sv);
        skey[u] = ((unsigned long long)dk << 16) | (unsigned)u;
        cnt += (dk < 0x7FFFFFFFu);          // sv > 0
    }
    atomicAdd(&sV, cnt);
    {
        int zb = blockIdx.x * 320;
        for (int z = zb + t; z < zb + 320; z += 256) out[z] = 0.0f;
    }
    __syncthreads();
    if (t == 0) *vcnt = (unsigned)sV;        // 128 identical stores: benign

    int grp = t >> 3;
    int jq  = t & 7;
    int i0 = blockIdx.x * 64 + grp * 2;
    int i1 = i0 + 1;
    unsigned long long k0 = skey[i0], k1 = skey[i1];
    int c0 = 0, c1 = 0;
    #pragma unroll 4
    for (int it = 0; it < 1024; ++it) {
        unsigned long long kj = skey[it * 8 + jq];
        c0 += (kj < k0);
        c1 += (kj < k1);
    }
    #pragma unroll
    for (int m = 1; m <= 4; m <<= 1) {
        c0 += __shfl_xor(c0, m);
        c1 += __shfl_xor(c1, m);
    }
    if (jq == 0) {
        scatter_one(i0, c0, k0, det, offsets, scales, boxes_srt, d_srt);
        scatter_one(i1, c1, k1, det, offsets, scales, boxes_srt, d_srt);
    }
}

// mask build: block (bx,by): rows [bx*32,+32), words [by*16,+16)
__global__ __launch_bounds__(256) void k_mask(
    const float4* __restrict__ boxes_srt,
    const unsigned int* __restrict__ vcnt,
    unsigned long long* __restrict__ mask)
{
    __shared__ float4 sb[16 * 65];   // padded stride: conflict-free
    __shared__ float  sa[16 * 65];
    int V = (int)*vcnt;
    int bx = blockIdx.x, by = blockIdx.y;
    if (bx * 32 >= V) return;                      // rows never consulted
    if (by * 1024 >= V) return;                    // cols never consulted
    if (by * 16 + 15 < (bx * 32) >> 6) return;     // fully below diagonal
    int nc = (V + 63) >> 6;
    int tid = threadIdx.x;
    int cbase = by * 1024;
    for (int u = tid; u < 1024; u += 256) {
        float4 b = boxes_srt[cbase + u];
        int c = u >> 6, jj = u & 63;
        sb[c * 65 + jj] = b;
        sa[c * 65 + jj] = __fmul_rn(fmaxf(__fsub_rn(b.z, b.x), 0.0f),
                                    fmaxf(__fsub_rn(b.w, b.y), 0.0f));
    }
    __syncthreads();
    int r = bx * 32 + (tid >> 3);
    if (r >= V) return;
    float4 bi = boxes_srt[r];
    float ai = __fmul_rn(fmaxf(__fsub_rn(bi.z, bi.x), 0.0f),
                         fmaxf(__fsub_rn(bi.w, bi.y), 0.0f));
    int rw = r >> 6;                 // words < rw of row r are never read
    #pragma unroll
    for (int k = 0; k < 2; ++k) {
        int wl = (tid & 7) + k * 8;              // local word 0..15
        int w = by * 16 + wl;
        if (w < rw || w >= nc) continue;
        unsigned long long bits = 0;
        #pragma unroll 4
        for (int jj = 0; jj < 64; ++jj) {
            float4 bj = sb[wl * 65 + jj];
            float aj = sa[wl * 65 + jj];
            float iw = fmaxf(__fsub_rn(fminf(bi.z, bj.z), fmaxf(bi.x, bj.x)), 0.0f);
            float ih = fmaxf(__fsub_rn(fminf(bi.w, bj.w), fmaxf(bi.y, bj.y)), 0.0f);
            float inter = __fmul_rn(iw, ih);
            float uni   = __fsub_rn(__fadd_rn(ai, aj), inter);
            float iou   = __fdiv_rn(inter, fmaxf(uni, 1e-9f));
            int j = w * 64 + jj;
            if (j > r && iou > NMS_T) bits |= 1ull << jj;
        }
        mask[(size_t)r * 128 + w] = bits;
    }
}

// ---- one depth-3 pipeline stage; broadcasts via readlane (VALU latency) ----
__device__ __forceinline__ void chunk_step(
    const unsigned long long* __restrict__ mask,
    const unsigned long long* __restrict__ zrow,
    unsigned long long* ck, int lane, int V, int nc, int T,
    unsigned long long& r0, unsigned long long& r1,
    unsigned long long& cN, unsigned long long& cN2,
    ulonglong2 (&p)[8],
    unsigned long long& d, unsigned long long& n1, unsigned long long& n2)
{
    int base = T * 64;
    // 1. apply pending rows (issued at T-3; >=3 chunks in flight)
    r0 |= p[0].x | p[1].x | p[2].x | p[3].x | p[4].x | p[5].x | p[6].x | p[7].x;
    r1 |= p[0].y | p[1].y | p[2].y | p[3].y | p[4].y | p[5].y | p[6].y | p[7].y;
    // 2. dead word for this chunk
    unsigned long long wv = (T & 1) ? rdlane64(r1, T >> 1) : rdlane64(r0, T >> 1);
    unsigned long long live = ~(wv | cN);
    int rem = V - base;
    if (rem < 64) live &= (1ull << rem) - 1ull;
    // 3. intra-chunk greedy resolve (ctz + readlane chain, ~30 cyc/keep)
    unsigned long long keptmask = 0;
    while (live) {                       // wave-uniform scalar loop
        int b = __builtin_ctzll(live);
        unsigned long long rm = rdlane64(d, b);
        keptmask |= 1ull << b;
        live &= ~rm & ~(1ull << b);
    }
    if (lane == 0) ck[T] = keptmask;
    // 4. carries to T+1 / T+2
    unsigned long long c1 = 0, c2 = 0, km = keptmask;
    while (km) {
        int b = __builtin_ctzll(km); km &= km - 1;
        c1 |= rdlane64(n1, b);
        c2 |= rdlane64(n2, b);
    }
    cN = cN2 | c1;
    cN2 = c2;
    // 5. prefetch chunk T+3's d/n1/n2 (unconditional; clamped, unused if OOB)
    {
        int pr = min(base + 192 + lane, M_TOT - 1);
        const unsigned long long* rp = mask + (size_t)pr * 128;
        d  = rp[min(T + 3, 127)];
        n1 = rp[min(T + 4, 127)];
        n2 = rp[min(T + 5, 127)];
    }
    // 6. 8 unconditional row loads, dummy-padded (applied at T+3)
    km = keptmask;
    #pragma unroll
    for (int q = 0; q < 8; ++q) {
        bool has = (km != 0ull);
        int b = has ? __builtin_ctzll(km) : 0;
        const ulonglong2* ptr = has
            ? ((const ulonglong2*)(mask + (size_t)(base + b) * 128) + lane)
            : ((const ulonglong2*)zrow + lane);
        p[q] = *ptr;
        km &= km - 1;                    // km==0 stays 0
    }
    // 7. overflow: >8 keeps in one chunk (P ~1%): immediate in-branch ORs
    if (km) {
        while (km) {
            int b = __builtin_ctzll(km); km &= km - 1;
            ulonglong2 s = *((const ulonglong2*)(mask + (size_t)(base + b) * 128) + lane);
            r0 |= s.x; r1 |= s.y;
        }
    }
}

__global__ __launch_bounds__(64) void k3_serial(
    const unsigned long long* __restrict__ mask,
    const unsigned long long* __restrict__ zrow,
    const float* __restrict__ d_srt,
    const unsigned int* __restrict__ vcnt,
    float* __restrict__ out)
{
    __shared__ unsigned long long ck[128];       // per-chunk keptmask
    int lane = threadIdx.x;
    int V = (int)*vcnt;
    int nc = (V + 63) >> 6;
    ck[lane] = 0ull; ck[64 + lane] = 0ull;
    unsigned long long r0 = 0, r1 = 0;           // lane L: dead words 2L,2L+1
    unsigned long long cN = 0, cN2 = 0;
    ulonglong2 pA[8], pB[8], pC[8];
    #pragma unroll
    for (int q = 0; q < 8; ++q) { pA[q] = ulonglong2{0,0}; pB[q] = ulonglong2{0,0}; pC[q] = ulonglong2{0,0}; }
    // prologue: slots for chunks 0,1,2 (clamped rows; junk unused if chunk >= nc)
    unsigned long long dA, n1A, n2A, dB, n1B, n2B, dC, n1C, n2C;
    {
        const unsigned long long* rp0 = mask + (size_t)lane * 128;
        dA = rp0[0]; n1A = rp0[1]; n2A = rp0[2];
        const unsigned long long* rp1 = mask + (size_t)(64 + lane) * 128;
        dB = rp1[1]; n1B = rp1[2]; n2B = rp1[3];
        const unsigned long long* rp2 = mask + (size_t)(128 + lane) * 128;
        dC = rp2[2]; n1C = rp2[3]; n2C = rp2[4];
    }
    for (int t = 0; t < nc; t += 3) {
        chunk_step(mask, zrow, ck, lane, V, nc, t,     r0, r1, cN, cN2, pA, dA, n1A, n2A);
        if (t + 1 < nc)
            chunk_step(mask, zrow, ck, lane, V, nc, t + 1, r0, r1, cN, cN2, pB, dB, n1B, n2B);
        if (t + 2 < nc)
            chunk_step(mask, zrow, ck, lane, V, nc, t + 2, r0, r1, cN, cN2, pC, dC, n1C, n2C);
    }
    __syncthreads();
    // output: expand per-chunk keptmasks (order irrelevant for stores)
    #pragma unroll
    for (int h = 0; h < 2; ++h) {
        unsigned long long m = ck[h * 64 + lane];
        while (m) {
            int b = __builtin_ctzll(m); m &= m - 1;
            int rr = (h * 64 + lane) * 64 + b;
            out[rr * 5 + 0] = d_srt[rr * 5 + 0];
            out[rr * 5 + 1] = d_srt[rr * 5 + 1];
            out[rr * 5 + 2] = d_srt[rr * 5 + 2];
            out[rr * 5 + 3] = d_srt[rr * 5 + 3];
            out[rr * 5 + 4] = d_srt[rr * 5 + 4];
        }
    }
}

extern "C" void kernel_launch(void* const* d_in, const int* in_sizes, int n_in,
                              void* d_out, int out_size, void* d_ws, size_t ws_size,
                              hipStream_t stream) {
    const float* det     = (const float*)d_in[0];
    const float* offsets = (const float*)d_in[1];
    const float* scales  = (const float*)d_in[2];
    const float* bounds  = (const float*)d_in[3];
    float* out = (float*)d_out;
    char* ws = (char*)d_ws;
    float4*             boxes = (float4*)(ws + WS_BOX);
    float*              d_srt = (float*)(ws + WS_D);
    unsigned int*       vcnt  = (unsigned int*)(ws + WS_VCNT);
    unsigned long long* zrow  = (unsigned long long*)(ws + WS_ZROW);
    unsigned long long* mask  = (unsigned long long*)(ws + WS_MASK);

    k2_rank<<<128, 256, 0, stream>>>(det, offsets, scales, bounds, boxes, d_srt, vcnt, zrow, out);
    k_mask<<<dim3(256, 8), 256, 0, stream>>>(boxes, vcnt, mask);
    k3_serial<<<1, 64, 0, stream>>>(mask, zrow, d_srt, vcnt, out);
}

// Round 9
// 160.106 us; speedup vs baseline: 4.0577x; 1.0492x over previous
//
#include <hip/hip_runtime.h>
#include <cstdint>

// DetNet NMS, round 9.
//   K2 (256 blocks): build keys, ballot-compact the VALID keys into LDS
//        (set identical across blocks; rank is order-independent), then rank
//        scan over V^2 (not M^2) with ds_read_b128. All 256 CUs busy.
//   K_MASK (256x8): unchanged (triangle/V-pruned, padded LDS).
//   K3 (1 wave): 128-candidate chunks (words 2T,2T+1 = one ulonglong2; both
//        words of a pair live in lane T of r0/r1). nc 63->32 halves fixed
//        overhead and doubles prefetch slack (~2 chunks ~1700 cyc >= ~900 HBM).
//        Depth-3 rotation for word-slots and row-slots; 16 dummy-padded row
//        loads/chunk; carries to T+1/T+2 via n1/n2 pairs at keep time;
//        broadcasts via v_readlane. Garbage in unwritten words only ever
//        lands on already-resolved bits (proof: lower-word of an upper-half
//        row is only applied when live_lo==0 / to words already consumed).
//
// All decision-critical FP math uses __f*_rn in exact ref op order (absmax
// 0.0 in rounds 1-4, 6-8).

#define M_TOT 8192
#define NMS_T 0.3f

// ws layout (bytes)
#define WS_BOX   65536      // float4[8192]
#define WS_D     196608     // float[40960]
#define WS_VCNT  360448     // u32
#define WS_ZROW  393216     // u64[128] dummy zero row (zeroed by k2)
#define WS_MASK  524288     // u64[8192*128] = 8 MB

typedef unsigned long long u64t;

__device__ __forceinline__ uint32_t desc_key(float sv) {
    uint32_t u = __float_as_uint(sv);
    uint32_t m = (u & 0x80000000u) ? ~u : (u | 0x80000000u); // asc monotone
    return ~m;                                               // desc
}

// wave-uniform-index 64-bit broadcast via v_readlane (VALU latency)
__device__ __forceinline__ u64t rdl64(u64t v, int sl) {
    unsigned lo = (unsigned)__builtin_amdgcn_readlane((int)(unsigned)v, sl);
    unsigned hi = (unsigned)__builtin_amdgcn_readlane((int)(unsigned)(v >> 32), sl);
    return ((u64t)hi << 32) | lo;
}

__device__ __forceinline__ int scatter_one(
    int i, int rank, u64t key,
    const float* __restrict__ det, const float* __restrict__ offsets,
    const float* __restrict__ scales,
    float4* __restrict__ boxes_srt, float* __restrict__ d_srt)
{
    uint32_t dkey = (uint32_t)(key >> 16);
    if (dkey >= 0x7FFFFFFFu) return 0;   // score <= 0: row stays zero
    int g = i >> 10;
    float d0 = __fadd_rn(offsets[g*5+0], __fmul_rn(det[i*5+0], scales[g*5+0]));
    float d1 = __fadd_rn(offsets[g*5+1], __fmul_rn(det[i*5+1], scales[g*5+1]));
    float d2 = __fadd_rn(offsets[g*5+2], __fmul_rn(det[i*5+2], scales[g*5+2]));
    float d3 = __fadd_rn(offsets[g*5+3], __fmul_rn(det[i*5+3], scales[g*5+3]));
    float d4 = __fadd_rn(offsets[g*5+4], __fmul_rn(det[i*5+4], scales[g*5+4]));
    d_srt[rank*5+0] = d0; d_srt[rank*5+1] = d1; d_srt[rank*5+2] = d2;
    d_srt[rank*5+3] = d3; d_srt[rank*5+4] = d4;
    float hw = __fmul_rn(d3, 0.5f), hh = __fmul_rn(d4, 0.5f);
    boxes_srt[rank] = make_float4(__fsub_rn(d1, hw), __fsub_rn(d2, hh),
                                  __fadd_rn(d1, hw), __fadd_rn(d2, hh));
    return 1;
}

__global__ __launch_bounds__(256) void k2_rank(
    const float* __restrict__ det, const float* __restrict__ offsets,
    const float* __restrict__ scales, const float* __restrict__ bounds,
    float4* __restrict__ boxes_srt, float* __restrict__ d_srt,
    unsigned int* __restrict__ vcnt, u64t* __restrict__ zrow,
    float* __restrict__ out)
{
    __shared__ u64t skey[M_TOT];   // compacted valid keys (<=V) + pad
    __shared__ float soff[40], sscl[40], sbnd[32];
    __shared__ int sTop;
    int t = threadIdx.x;
    int lane = t & 63;
    if (t == 0) sTop = 0;
    if (t < 40) { soff[t] = offsets[t]; sscl[t] = scales[t]; }
    if (t < 32) { sbnd[t] = bounds[t]; }
    if (blockIdx.x == 0 && t < 128) zrow[t] = 0ull;   // dummy row for k3
    __syncthreads();

    // ---- build + ballot-compact valid keys (set identical per block) ----
    #pragma unroll 4
    for (int s = 0; s < 32; ++s) {
        int u = s * 256 + t;
        int g = u >> 10;
        float raw_s = det[u * 5 + 0];
        float cx    = det[u * 5 + 1];
        float cy    = det[u * 5 + 2];
        float score = __fadd_rn(soff[g * 5 + 0], __fmul_rn(raw_s, sscl[g * 5 + 0]));
        bool valid = (cx < sbnd[g*4+1]) && (cx > sbnd[g*4+0]) &&
                     (cy < sbnd[g*4+3]) && (cy > sbnd[g*4+2]);
        float sv = valid ? score : -1.0f;
        uint32_t dk = desc_key(sv);
        bool push = dk < 0x7FFFFFFFu;    // valid && score > 0
        u64t key = ((u64t)dk << 16) | (unsigned)u;
        u64t bal = __ballot(push);
        if (bal) {
            int lw = 0;
            if (lane == 0) lw = atomicAdd(&sTop, __popcll(bal));
            int wbase = __builtin_amdgcn_readfirstlane(lw);
            if (push) {
                int off = __popcll(bal & ((1ull << lane) - 1ull));
                skey[wbase + off] = key;
            }
        }
    }
    __syncthreads();
    int V = sTop;
    int Vpad = (V + 15) & ~15;
    if (t < Vpad - V) skey[V + t] = ~0ull;     // pad: never < any real key
    {   // zero this block's slice of out (harness poisons to 0xAA)
        int zb = blockIdx.x * 160;
        for (int z = zb + t; z < zb + 160; z += 256) out[z] = 0.0f;
    }
    __syncthreads();
    if (t == 0) *vcnt = (unsigned)V;           // 256 identical stores: benign

    // ---- rank scan: 32 groups of 8 lanes; group -> one ORIGINAL index i ----
    int grp = t >> 3;
    int jq  = t & 7;
    int i = blockIdx.x * 32 + grp;             // 256*32 = 8192
    int g = i >> 10;
    float raw_s = det[i * 5 + 0];
    float cx    = det[i * 5 + 1];
    float cy    = det[i * 5 + 2];
    float score = __fadd_rn(soff[g * 5 + 0], __fmul_rn(raw_s, sscl[g * 5 + 0]));
    bool valid = (cx < sbnd[g*4+1]) && (cx > sbnd[g*4+0]) &&
                 (cy < sbnd[g*4+3]) && (cy > sbnd[g*4+2]);
    float sv = valid ? score : -1.0f;
    uint32_t dk = desc_key(sv);
    u64t ki = ((u64t)dk << 16) | (unsigned)i;
    const ulonglong2* skey2 = (const ulonglong2*)skey;
    int c = 0;
    int nit = Vpad >> 4;                       // 16 keys per group-iteration
    #pragma unroll 4
    for (int it = 0; it < nit; ++it) {
        ulonglong2 kj = skey2[it * 8 + jq];    // group reads 128B contiguous
        c += (kj.x < ki) + (kj.y < ki);
    }
    c += __shfl_xor(c, 1);
    c += __shfl_xor(c, 2);
    c += __shfl_xor(c, 4);
    if (jq == 0)
        scatter_one(i, c, ki, det, offsets, scales, boxes_srt, d_srt);
}

// mask build: block (bx,by): rows [bx*32,+32), words [by*16,+16)
__global__ __launch_bounds__(256) void k_mask(
    const float4* __restrict__ boxes_srt,
    const unsigned int* __restrict__ vcnt,
    u64t* __restrict__ mask)
{
    __shared__ float4 sb[16 * 65];   // padded stride: conflict-free
    __shared__ float  sa[16 * 65];
    int V = (int)*vcnt;
    int bx = blockIdx.x, by = blockIdx.y;
    if (bx * 32 >= V) return;
    if (by * 1024 >= V) return;
    if (by * 16 + 15 < (bx * 32) >> 6) return;
    int nc = (V + 63) >> 6;
    int tid = threadIdx.x;
    int cbase = by * 1024;
    for (int u = tid; u < 1024; u += 256) {
        float4 b = boxes_srt[cbase + u];
        int c = u >> 6, jj = u & 63;
        sb[c * 65 + jj] = b;
        sa[c * 65 + jj] = __fmul_rn(fmaxf(__fsub_rn(b.z, b.x), 0.0f),
                                    fmaxf(__fsub_rn(b.w, b.y), 0.0f));
    }
    __syncthreads();
    int r = bx * 32 + (tid >> 3);
    if (r >= V) return;
    float4 bi = boxes_srt[r];
    float ai = __fmul_rn(fmaxf(__fsub_rn(bi.z, bi.x), 0.0f),
                         fmaxf(__fsub_rn(bi.w, bi.y), 0.0f));
    int rw = r >> 6;
    #pragma unroll
    for (int k = 0; k < 2; ++k) {
        int wl = (tid & 7) + k * 8;
        int w = by * 16 + wl;
        if (w < rw || w >= nc) continue;
        u64t bits = 0;
        #pragma unroll 4
        for (int jj = 0; jj < 64; ++jj) {
            float4 bj = sb[wl * 65 + jj];
            float aj = sa[wl * 65 + jj];
            float iw = fmaxf(__fsub_rn(fminf(bi.z, bj.z), fmaxf(bi.x, bj.x)), 0.0f);
            float ih = fmaxf(__fsub_rn(fminf(bi.w, bj.w), fmaxf(bi.y, bj.y)), 0.0f);
            float inter = __fmul_rn(iw, ih);
            float uni   = __fsub_rn(__fadd_rn(ai, aj), inter);
            float iou   = __fdiv_rn(inter, fmaxf(uni, 1e-9f));
            int j = w * 64 + jj;
            if (j > r && iou > NMS_T) bits |= 1ull << jj;
        }
        mask[(size_t)r * 128 + w] = bits;
    }
}

// word-slot for one 128-chunk: dl/dh = word-pair 2T,2T+1 of rows base+lane /
// base+64+lane; n1*/n2* = pairs for chunks T+1 / T+2 (carry sources).
struct WSlot { ulonglong2 dl, dh, n1l, n1h, n2l, n2h; };

__device__ __forceinline__ void fill_words(
    const u64t* __restrict__ mask, int lane, int T, WSlot& w)
{
    int rl = min(T * 128 + lane,      M_TOT - 1);
    int rh = min(T * 128 + 64 + lane, M_TOT - 1);
    const ulonglong2* mrl = (const ulonglong2*)(mask + (size_t)rl * 128);
    const ulonglong2* mrh = (const ulonglong2*)(mask + (size_t)rh * 128);
    int p0 = min(T,     63);
    int p1 = min(T + 1, 63);
    int p2 = min(T + 2, 63);
    w.dl  = mrl[p0]; w.dh  = mrh[p0];
    w.n1l = mrl[p1]; w.n1h = mrh[p1];
    w.n2l = mrl[p2]; w.n2h = mrh[p2];
}

// one 128-candidate pipeline stage (depth-3 rotation at the call site)
__device__ __forceinline__ void step(
    const u64t* __restrict__ mask, const u64t* __restrict__ zrow,
    u64t* ck, int lane, int V, int nc, int T,
    u64t& r0, u64t& r1,
    u64t& cA_lo, u64t& cA_hi, u64t& cB_lo, u64t& cB_hi,
    ulonglong2 (&p)[16], WSlot& w)
{
    int base = T * 128;
    // 1. apply rows kept at T-3 (loads in flight ~2.7 chunks)
    u64t a0 = 0, a1 = 0;
    #pragma unroll
    for (int q = 0; q < 16; ++q) { a0 |= p[q].x; a1 |= p[q].y; }
    r0 |= a0; r1 |= a1;
    // 2. dead pair: words 2T (r0) and 2T+1 (r1), both in lane T
    u64t live_lo = ~(rdl64(r0, T) | cA_lo);
    u64t live_hi = ~(rdl64(r1, T) | cA_hi);
    int rem = V - base;
    if (rem < 128) {
        live_lo &= (rem >= 64) ? ~0ull : ((1ull << rem) - 1ull);
        int rh = rem - 64;
        live_hi &= (rh >= 64) ? ~0ull : ((rh <= 0) ? 0ull : ((1ull << rh) - 1ull));
    }
    // 3. resolve (ctz + readlane chains; n-reads off the critical path)
    u64t km_lo = 0, km_hi = 0, c1l = 0, c1h = 0, c2l = 0, c2h = 0;
    while (live_lo | live_hi) {
        if (live_lo) {                    // wave-uniform branch
            int bs = __builtin_amdgcn_readfirstlane(__builtin_ctzll(live_lo));
            u64t rml = rdl64(w.dl.x, bs), rmh = rdl64(w.dl.y, bs);
            c1l |= rdl64(w.n1l.x, bs); c1h |= rdl64(w.n1l.y, bs);
            c2l |= rdl64(w.n2l.x, bs); c2h |= rdl64(w.n2l.y, bs);
            km_lo |= 1ull << bs;
            live_lo &= ~rml & ~(1ull << bs);
            live_hi &= ~rmh;
        } else {
            int bs = __builtin_amdgcn_readfirstlane(__builtin_ctzll(live_hi));
            u64t rmh = rdl64(w.dh.y, bs); // w.dh.x (word 2T) may be garbage:
                                          // only affects live_lo which is 0
            c1l |= rdl64(w.n1h.x, bs); c1h |= rdl64(w.n1h.y, bs);
            c2l |= rdl64(w.n2h.x, bs); c2h |= rdl64(w.n2h.y, bs);
            km_hi |= 1ull << bs;
            live_hi &= ~rmh & ~(1ull << bs);
        }
    }
    if (lane == 0) { ck[2 * T] = km_lo; ck[2 * T + 1] = km_hi; }
    cA_lo = cB_lo | c1l; cA_hi = cB_hi | c1h;
    cB_lo = c2l;         cB_hi = c2h;
    // 4. 16 row loads, dummy-padded (applied at T+3)
    u64t kl = km_lo, kh = km_hi;
    #pragma unroll
    for (int q = 0; q < 16; ++q) {
        const ulonglong2* ptr;
        if (kl) {
            int b = __builtin_ctzll(kl); kl &= kl - 1;
            ptr = (const ulonglong2*)(mask + (size_t)(base + b) * 128) + lane;
        } else if (kh) {
            int b = __builtin_ctzll(kh); kh &= kh - 1;
            ptr = (const ulonglong2*)(mask + (size_t)(base + 64 + b) * 128) + lane;
        } else {
            ptr = (const ulonglong2*)zrow + lane;
        }
        p[q] = *ptr;
    }
    // 5. overflow: >16 keeps in one 128-chunk (P ~0.2%): immediate ORs
    if (kl | kh) {
        while (kl) {
            int b = __builtin_ctzll(kl); kl &= kl - 1;
            ulonglong2 s = *((const ulonglong2*)(mask + (size_t)(base + b) * 128) + lane);
            r0 |= s.x; r1 |= s.y;
        }
        while (kh) {
            int b = __builtin_ctzll(kh); kh &= kh - 1;
            ulonglong2 s = *((const ulonglong2*)(mask + (size_t)(base + 64 + b) * 128) + lane);
            r0 |= s.x; r1 |= s.y;
        }
    }
    // 6. prefetch word-slot for chunk T+3 (same registers: WAR after last use)
    fill_words(mask, lane, T + 3, w);
}

__global__ __launch_bounds__(64) void k3_serial(
    const u64t* __restrict__ mask, const u64t* __restrict__ zrow,
    const float* __restrict__ d_srt, const unsigned int* __restrict__ vcnt,
    float* __restrict__ out)
{
    __shared__ u64t ck[128];                 // per-64-word keptmask
    int lane = threadIdx.x;
    int V = (int)*vcnt;
    int nc = (V + 127) >> 7;                 // 128-candidate chunks, <=64
    ck[lane] = 0ull; ck[64 + lane] = 0ull;
    u64t r0 = 0, r1 = 0;                     // lane L: dead words 2L, 2L+1
    u64t cA_lo = 0, cA_hi = 0, cB_lo = 0, cB_hi = 0;
    ulonglong2 pA[16], pB[16], pC[16];
    #pragma unroll
    for (int q = 0; q < 16; ++q) {
        pA[q] = ulonglong2{0, 0}; pB[q] = ulonglong2{0, 0}; pC[q] = ulonglong2{0, 0};
    }
    WSlot WA, WB, WC;
    fill_words(mask, lane, 0, WA);
    fill_words(mask, lane, 1, WB);
    fill_words(mask, lane, 2, WC);
    for (int t = 0; t < nc; t += 3) {
        step(mask, zrow, ck, lane, V, nc, t,     r0, r1, cA_lo, cA_hi, cB_lo, cB_hi, pA, WA);
        if (t + 1 < nc)
            step(mask, zrow, ck, lane, V, nc, t + 1, r0, r1, cA_lo, cA_hi, cB_lo, cB_hi, pB, WB);
        if (t + 2 < nc)
            step(mask, zrow, ck, lane, V, nc, t + 2, r0, r1, cA_lo, cA_hi, cB_lo, cB_hi, pC, WC);
    }
    __syncthreads();
    #pragma unroll
    for (int h = 0; h < 2; ++h) {
        u64t m = ck[h * 64 + lane];
        while (m) {
            int b = __builtin_ctzll(m); m &= m - 1;
            int rr = (h * 64 + lane) * 64 + b;
            out[rr * 5 + 0] = d_srt[rr * 5 + 0];
            out[rr * 5 + 1] = d_srt[rr * 5 + 1];
            out[rr * 5 + 2] = d_srt[rr * 5 + 2];
            out[rr * 5 + 3] = d_srt[rr * 5 + 3];
            out[rr * 5 + 4] = d_srt[rr * 5 + 4];
        }
    }
}

extern "C" void kernel_launch(void* const* d_in, const int* in_sizes, int n_in,
                              void* d_out, int out_size, void* d_ws, size_t ws_size,
                              hipStream_t stream) {
    const float* det     = (const float*)d_in[0];
    const float* offsets = (const float*)d_in[1];
    const float* scales  = (const float*)d_in[2];
    const float* bounds  = (const float*)d_in[3];
    float* out = (float*)d_out;
    char* ws = (char*)d_ws;
    float4*       boxes = (float4*)(ws + WS_BOX);
    float*        d_srt = (float*)(ws + WS_D);
    unsigned int* vcnt  = (unsigned int*)(ws + WS_VCNT);
    u64t*         zrow  = (u64t*)(ws + WS_ZROW);
    u64t*         mask  = (u64t*)(ws + WS_MASK);

    k2_rank<<<256, 256, 0, stream>>>(det, offsets, scales, bounds, boxes, d_srt, vcnt, zrow, out);
    k_mask<<<dim3(256, 8), 256, 0, stream>>>(boxes, vcnt, mask);
    k3_serial<<<1, 64, 0, stream>>>(mask, zrow, d_srt, vcnt, out);
}